// Round 11
// baseline (2382.036 us; speedup 1.0000x reference)
//
#include <hip/hip_runtime.h>
#include <math.h>

static const int PRED  = 100000;
static const int TOTAL = 120000;
static const int ITEM  = 100000;
static const int NUI   = PRED + ITEM;    // 200000
static const int NODES = TOTAL + ITEM;   // 220000
#define BN_EPS 1e-5f

__device__ inline float lrelu(float v, float s) { return fmaxf(v, s * v); }

// ---------------- batchnorm ----------------
__global__ void k_bn_stats(const float* __restrict__ x, int n, float* __restrict__ sums) {
  __shared__ float ls[256], ls2[256];
  int t = threadIdx.x;
  int col = t & 63;
  float s = 0.f, s2 = 0.f;
  for (int r = blockIdx.x * 4 + (t >> 6); r < n; r += gridDim.x * 4) {
    float v = x[(size_t)r * 64 + col];
    s += v; s2 += v * v;
  }
  ls[t] = s; ls2[t] = s2;
  __syncthreads();
  if (t < 64) {
    atomicAdd(&sums[t],      ls[t] + ls[t + 64] + ls[t + 128] + ls[t + 192]);
    atomicAdd(&sums[64 + t], ls2[t] + ls2[t + 64] + ls2[t + 128] + ls2[t + 192]);
  }
}

__global__ void k_bn_apply(const float* __restrict__ x, float* __restrict__ y,
                           const float* __restrict__ sums,
                           const float* __restrict__ g, const float* __restrict__ b,
                           int n, int relu) {
  size_t tot4 = (size_t)n * 16;
  size_t i = (size_t)blockIdx.x * blockDim.x + threadIdx.x;
  size_t st = (size_t)gridDim.x * blockDim.x;
  float inv_n = 1.f / (float)n;
  const float4* x4 = (const float4*)x;
  float4* y4 = (float4*)y;
  for (; i < tot4; i += st) {
    int c4 = (int)(i & 15) * 4;
    float4 v = x4[i];
    float4 o;
    #pragma unroll
    for (int j = 0; j < 4; ++j) {
      int c = c4 + j;
      float mean = sums[c] * inv_n;
      float var = fmaxf(sums[64 + c] * inv_n - mean * mean, 0.f);
      float vv = (j == 0) ? v.x : (j == 1) ? v.y : (j == 2) ? v.z : v.w;
      float oo = (vv - mean) * rsqrtf(var + BN_EPS) * g[c] + b[c];
      if (relu) oo = lrelu(oo, 0.01f);
      if (j == 0) o.x = oo; else if (j == 1) o.y = oo; else if (j == 2) o.z = oo; else o.w = oo;
    }
    y4[i] = o;
  }
}

__global__ void k_bn0_apply(const float* __restrict__ x, float* __restrict__ e_tot,
                            float* __restrict__ uie, const float* __restrict__ sums,
                            const float* __restrict__ g, const float* __restrict__ b) {
  size_t tot4 = (size_t)NODES * 16;
  size_t i = (size_t)blockIdx.x * blockDim.x + threadIdx.x;
  size_t st = (size_t)gridDim.x * blockDim.x;
  float inv_n = 1.f / (float)NODES;
  const float4* x4 = (const float4*)x;
  float4* e4 = (float4*)e_tot;
  float4* u4 = (float4*)uie;
  for (; i < tot4; i += st) {
    int c4 = (int)(i & 15) * 4;
    size_t row = i >> 4;
    float4 v = x4[i];
    float4 o;
    #pragma unroll
    for (int j = 0; j < 4; ++j) {
      int c = c4 + j;
      float mean = sums[c] * inv_n;
      float var = fmaxf(sums[64 + c] * inv_n - mean * mean, 0.f);
      float vv = (j == 0) ? v.x : (j == 1) ? v.y : (j == 2) ? v.z : v.w;
      float oo = (vv - mean) * rsqrtf(var + BN_EPS) * g[c] + b[c];
      if (j == 0) o.x = oo; else if (j == 1) o.y = oo; else if (j == 2) o.z = oo; else o.w = oo;
    }
    if (row < (size_t)TOTAL) e4[i] = o;
    else u4[((row - TOTAL) + PRED) * 16 + (i & 15)] = o;
    if (row < (size_t)PRED) u4[i] = o;
  }
}

// ---------------- fused GEMMs (64 rows/block, 256 threads, 2x8/thread) ----------------
__global__ __launch_bounds__(256) void k_gemm_dual(const float* __restrict__ A,
    const float* __restrict__ Wl, const float* __restrict__ bl,
    const float* __restrict__ Wr, const float* __restrict__ br,
    float* __restrict__ FS, float* __restrict__ FD, int n) {
  __shared__ float As[64][65];
  __shared__ float Ws[64][68];
  int t = threadIdx.x;
  int row0 = blockIdx.x * 64;
  for (int i = t; i < 1024; i += 256) {
    int r = i >> 4, c = (i & 15) * 4, gr = row0 + r;
    float4 a;
    if (gr < n) a = *(const float4*)&A[(size_t)gr * 64 + c];
    else { a.x = a.y = a.z = a.w = 0.f; }
    As[r][c] = a.x; As[r][c + 1] = a.y; As[r][c + 2] = a.z; As[r][c + 3] = a.w;
  }
  int cg = (t & 7) * 8;
  int rg = (t >> 3) * 2;
  for (int s = 0; s < 2; ++s) {
    const float* Wm = s ? Wr : Wl;
    const float* bias = s ? br : bl;
    __syncthreads();
    for (int i = t; i < 4096; i += 256) Ws[i >> 6][i & 63] = Wm[i];
    __syncthreads();
    float bb[8];
    *(float4*)&bb[0] = *(const float4*)&bias[cg];
    *(float4*)&bb[4] = *(const float4*)&bias[cg + 4];
    float acc[2][8];
    #pragma unroll
    for (int i = 0; i < 2; ++i)
      #pragma unroll
      for (int j = 0; j < 8; ++j) acc[i][j] = bb[j];
    for (int k = 0; k < 64; ++k) {
      float w[8], a[2];
      *(float4*)&w[0] = *(const float4*)&Ws[k][cg];
      *(float4*)&w[4] = *(const float4*)&Ws[k][cg + 4];
      #pragma unroll
      for (int i = 0; i < 2; ++i) a[i] = As[rg + i][k];
      #pragma unroll
      for (int i = 0; i < 2; ++i)
        #pragma unroll
        for (int j = 0; j < 8; ++j)
          acc[i][j] += a[i] * w[j];
    }
    float* C = s ? FD : FS;
    #pragma unroll
    for (int i = 0; i < 2; ++i) {
      int gr = row0 + rg + i;
      if (gr < n) {
        float4 o0, o1;
        o0.x = acc[i][0]; o0.y = acc[i][1]; o0.z = acc[i][2]; o0.w = acc[i][3];
        o1.x = acc[i][4]; o1.y = acc[i][5]; o1.z = acc[i][6]; o1.w = acc[i][7];
        *(float4*)&C[(size_t)gr * 64 + cg] = o0;
        *(float4*)&C[(size_t)gr * 64 + cg + 4] = o1;
      }
    }
  }
}

// concat GEMM: C = A1@W[0:64] + A2@W[64:128] (+A3@W[128:192]) + bias, optional lrelu + stats
__global__ __launch_bounds__(256) void k_gemm_cat(const float* __restrict__ A1,
    const float* __restrict__ A2, const float* __restrict__ A3,
    const float* __restrict__ Wm, const float* __restrict__ bias,
    float* __restrict__ C, int n, int nseg, int relu, float* __restrict__ stats) {
  __shared__ float As[64][65];
  __shared__ float Ws[64][68];
  __shared__ float st[128];
  int t = threadIdx.x;
  int row0 = blockIdx.x * 64;
  int cg = (t & 7) * 8;
  int rg = (t >> 3) * 2;
  float bb[8];
  *(float4*)&bb[0] = *(const float4*)&bias[cg];
  *(float4*)&bb[4] = *(const float4*)&bias[cg + 4];
  float acc[2][8];
  #pragma unroll
  for (int i = 0; i < 2; ++i)
    #pragma unroll
    for (int j = 0; j < 8; ++j) acc[i][j] = bb[j];
  for (int s = 0; s < nseg; ++s) {
    const float* A = (s == 0) ? A1 : (s == 1) ? A2 : A3;
    __syncthreads();
    for (int i = t; i < 4096; i += 256) Ws[i >> 6][i & 63] = Wm[s * 4096 + i];
    for (int i = t; i < 1024; i += 256) {
      int r = i >> 4, c = (i & 15) * 4, gr = row0 + r;
      float4 a;
      if (gr < n) a = *(const float4*)&A[(size_t)gr * 64 + c];
      else { a.x = a.y = a.z = a.w = 0.f; }
      As[r][c] = a.x; As[r][c + 1] = a.y; As[r][c + 2] = a.z; As[r][c + 3] = a.w;
    }
    __syncthreads();
    for (int k = 0; k < 64; ++k) {
      float w[8], a[2];
      *(float4*)&w[0] = *(const float4*)&Ws[k][cg];
      *(float4*)&w[4] = *(const float4*)&Ws[k][cg + 4];
      #pragma unroll
      for (int i = 0; i < 2; ++i) a[i] = As[rg + i][k];
      #pragma unroll
      for (int i = 0; i < 2; ++i)
        #pragma unroll
        for (int j = 0; j < 8; ++j)
          acc[i][j] += a[i] * w[j];
    }
  }
  float csum[8], csq[8];
  #pragma unroll
  for (int j = 0; j < 8; ++j) { csum[j] = 0.f; csq[j] = 0.f; }
  #pragma unroll
  for (int i = 0; i < 2; ++i) {
    int gr = row0 + rg + i;
    if (gr < n) {
      #pragma unroll
      for (int j = 0; j < 8; ++j) {
        float o = acc[i][j];
        if (relu) o = lrelu(o, 0.01f);
        acc[i][j] = o;
        csum[j] += o;
        csq[j] += o * o;
      }
      float4 o0, o1;
      o0.x = acc[i][0]; o0.y = acc[i][1]; o0.z = acc[i][2]; o0.w = acc[i][3];
      o1.x = acc[i][4]; o1.y = acc[i][5]; o1.z = acc[i][6]; o1.w = acc[i][7];
      *(float4*)&C[(size_t)gr * 64 + cg] = o0;
      *(float4*)&C[(size_t)gr * 64 + cg + 4] = o1;
    }
  }
  if (stats) {
    __syncthreads();
    if (t < 128) st[t] = 0.f;
    __syncthreads();
    #pragma unroll
    for (int j = 0; j < 8; ++j) {
      atomicAdd(&st[cg + j], csum[j]);
      atomicAdd(&st[64 + cg + j], csq[j]);
    }
    __syncthreads();
    if (t < 128) atomicAdd(&stats[t], st[t]);
  }
}

// final MLP: a=lrelu(bnA(rawA)); b=lrelu(bnB(rawB)); A1=a*b*softmax(a); A2=a; stats on raw C.
__global__ __launch_bounds__(256) void k_mlp_final(const float* __restrict__ rawA,
    const float* __restrict__ rawB,
    const float* __restrict__ sA, const float* __restrict__ gA, const float* __restrict__ bA,
    const float* __restrict__ sB, const float* __restrict__ gB, const float* __restrict__ bB,
    float invn, const float* __restrict__ Wm, const float* __restrict__ bias,
    float* __restrict__ C, int n, float* __restrict__ stats) {
  __shared__ float As[64][65];
  __shared__ float Ws[64][68];
  __shared__ float st[128];
  int t = threadIdx.x;
  int row0 = blockIdx.x * 64;
  int cg = (t & 7) * 8;
  int rg = (t >> 3) * 2;
  float bb[8];
  *(float4*)&bb[0] = *(const float4*)&bias[cg];
  *(float4*)&bb[4] = *(const float4*)&bias[cg + 4];
  float acc[2][8];
  #pragma unroll
  for (int i = 0; i < 2; ++i)
    #pragma unroll
    for (int j = 0; j < 8; ++j) acc[i][j] = bb[j];
  for (int s = 0; s < 2; ++s) {
    __syncthreads();
    for (int i = t; i < 4096; i += 256) Ws[i >> 6][i & 63] = Wm[s * 4096 + i];
    for (int i = t; i < 1024; i += 256) {
      int r = i >> 4, c = (i & 15) * 4, gr = row0 + r;
      float av[4], out4[4];
      #pragma unroll
      for (int j = 0; j < 4; ++j) {
        int ch = c + j;
        float va = (gr < n) ? rawA[(size_t)gr * 64 + ch] : 0.f;
        float mean = sA[ch] * invn;
        float var = fmaxf(sA[64 + ch] * invn - mean * mean, 0.f);
        float aa = lrelu((va - mean) * rsqrtf(var + BN_EPS) * gA[ch] + bA[ch], 0.01f);
        av[j] = (gr < n) ? aa : 0.f;
      }
      if (s == 1) {
        out4[0] = av[0]; out4[1] = av[1]; out4[2] = av[2]; out4[3] = av[3];
      } else {
        float bv[4];
        #pragma unroll
        for (int j = 0; j < 4; ++j) {
          int ch = c + j;
          float vb = (gr < n) ? rawB[(size_t)gr * 64 + ch] : 0.f;
          float mean = sB[ch] * invn;
          float var = fmaxf(sB[64 + ch] * invn - mean * mean, 0.f);
          float bbv = lrelu((vb - mean) * rsqrtf(var + BN_EPS) * gB[ch] + bB[ch], 0.01f);
          bv[j] = (gr < n) ? bbv : 0.f;
        }
        float mx = fmaxf(fmaxf(av[0], av[1]), fmaxf(av[2], av[3]));
        mx = fmaxf(mx, __shfl_xor(mx, 1));
        mx = fmaxf(mx, __shfl_xor(mx, 2));
        mx = fmaxf(mx, __shfl_xor(mx, 4));
        mx = fmaxf(mx, __shfl_xor(mx, 8));
        float e[4];
        float ss = 0.f;
        #pragma unroll
        for (int j = 0; j < 4; ++j) { e[j] = expf(av[j] - mx); ss += e[j]; }
        ss += __shfl_xor(ss, 1);
        ss += __shfl_xor(ss, 2);
        ss += __shfl_xor(ss, 4);
        ss += __shfl_xor(ss, 8);
        float inv = 1.f / ss;
        #pragma unroll
        for (int j = 0; j < 4; ++j) out4[j] = av[j] * bv[j] * e[j] * inv;
      }
      As[r][c] = out4[0]; As[r][c + 1] = out4[1]; As[r][c + 2] = out4[2]; As[r][c + 3] = out4[3];
    }
    __syncthreads();
    for (int k = 0; k < 64; ++k) {
      float w[8], a[2];
      *(float4*)&w[0] = *(const float4*)&Ws[k][cg];
      *(float4*)&w[4] = *(const float4*)&Ws[k][cg + 4];
      #pragma unroll
      for (int i = 0; i < 2; ++i) a[i] = As[rg + i][k];
      #pragma unroll
      for (int i = 0; i < 2; ++i)
        #pragma unroll
        for (int j = 0; j < 8; ++j)
          acc[i][j] += a[i] * w[j];
    }
  }
  float csum[8], csq[8];
  #pragma unroll
  for (int j = 0; j < 8; ++j) { csum[j] = 0.f; csq[j] = 0.f; }
  #pragma unroll
  for (int i = 0; i < 2; ++i) {
    int gr = row0 + rg + i;
    if (gr < n) {
      #pragma unroll
      for (int j = 0; j < 8; ++j) {
        float o = acc[i][j];
        csum[j] += o;
        csq[j] += o * o;
      }
      float4 o0, o1;
      o0.x = acc[i][0]; o0.y = acc[i][1]; o0.z = acc[i][2]; o0.w = acc[i][3];
      o1.x = acc[i][4]; o1.y = acc[i][5]; o1.z = acc[i][6]; o1.w = acc[i][7];
      *(float4*)&C[(size_t)gr * 64 + cg] = o0;
      *(float4*)&C[(size_t)gr * 64 + cg + 4] = o1;
    }
  }
  __syncthreads();
  if (t < 128) st[t] = 0.f;
  __syncthreads();
  #pragma unroll
  for (int j = 0; j < 8; ++j) {
    atomicAdd(&st[cg + j], csum[j]);
    atomicAdd(&st[64 + cg + j], csq[j]);
  }
  __syncthreads();
  if (t < 128) atomicAdd(&stats[t], st[t]);
}

// ---------------- CSR build ----------------
__global__ __launch_bounds__(512) void k_bhist(const int* __restrict__ dst, int* __restrict__ M,
                                               int E, int nbuck, int chunk) {
  __shared__ int h[1600];
  int t = threadIdx.x, b = blockIdx.x;
  for (int k = t; k < nbuck; k += 512) h[k] = 0;
  __syncthreads();
  int beg = b * chunk, end = min(E, beg + chunk);
  for (int i = beg + t; i < end; i += 512) atomicAdd(&h[dst[i] >> 7], 1);
  __syncthreads();
  for (int k = t; k < nbuck; k += 512) M[k * 64 + b] = h[k];
}

__global__ __launch_bounds__(1024) void k_scan_one(int* __restrict__ cnts, int L) {
  __shared__ int wsum[16];
  __shared__ int carry_s;
  int t = threadIdx.x, lane = t & 63, w = t >> 6;
  if (t == 0) carry_s = 0;
  __syncthreads();
  for (int base = 0; base < L; base += 1024) {
    int i = base + t;
    int v = (i < L) ? cnts[i] : 0;
    int x = v;
    #pragma unroll
    for (int o = 1; o < 64; o <<= 1) {
      int y = __shfl_up(x, o);
      if (lane >= o) x += y;
    }
    if (lane == 63) wsum[w] = x;
    __syncthreads();
    int carry = carry_s;
    int wadd = 0;
    #pragma unroll
    for (int j = 0; j < 16; ++j) { int sv = wsum[j]; if (j < w) wadd += sv; }
    int incl = x + wadd + carry;
    if (i < L) cnts[i] = incl - v;
    __syncthreads();
    if (t == 1023) carry_s = incl;
    __syncthreads();
  }
}

__global__ __launch_bounds__(512) void k_bscatter(const int* __restrict__ src, const int* __restrict__ dst,
                                                  const int* __restrict__ M, unsigned int* __restrict__ tmp,
                                                  int E, int nbuck, int chunk) {
  __shared__ int cur[1600];
  int t = threadIdx.x, b = blockIdx.x;
  for (int k = t; k < nbuck; k += 512) cur[k] = M[k * 64 + b];
  __syncthreads();
  int beg = b * chunk, end = min(E, beg + chunk);
  for (int i = beg + t; i < end; i += 512) {
    int d = dst[i];
    int pos = atomicAdd(&cur[d >> 7], 1);
    tmp[pos] = ((unsigned int)(d & 127) << 25) | (unsigned int)src[i];
  }
}

__global__ __launch_bounds__(256) void k_bfinal(const unsigned int* __restrict__ tmp,
                                                const int* __restrict__ M,
                                                int* __restrict__ offs, int* __restrict__ csr,
                                                int E, int nbuck, int n,
                                                float* __restrict__ dinvOut) {
  __shared__ int h[128];
  int t = threadIdx.x, k = blockIdx.x;
  int base = M[k * 64];
  int next = (k + 1 < nbuck) ? M[(k + 1) * 64] : E;
  if (t < 128) h[t] = 0;
  __syncthreads();
  for (int i = base + t; i < next; i += 256) atomicAdd(&h[tmp[i] >> 25], 1);
  __syncthreads();
  if (t == 0) { int s = 0; for (int j = 0; j < 128; ++j) { int c = h[j]; h[j] = s; s += c; } }
  __syncthreads();
  int r0 = k << 7;
  int hstart = 0, hnext = 0;
  if (t < 128) {
    hstart = h[t];
    hnext = (t < 127) ? h[t + 1] : (next - base);
  }
  if (t < 128 && r0 + t < n) {
    offs[r0 + t] = base + hstart;
    if (dinvOut) dinvOut[r0 + t] = rsqrtf(fmaxf((float)(hnext - hstart), 1.f));
  }
  if (k == nbuck - 1 && t == 0) offs[n] = E;
  __syncthreads();
  for (int i = base + t; i < next; i += 256) {
    unsigned int v = tmp[i];
    int rl = (int)(v >> 25);
    int pos = base + atomicAdd(&h[rl], 1);
    csr[pos] = (int)(v & 0x01FFFFFFu);
  }
}

// ---------------- fused GAT ----------------
__global__ __launch_bounds__(256) void k_gat_fused(const float* __restrict__ fs,
                                                   const float* __restrict__ fd,
                                                   const float* __restrict__ attn,
                                                   const int* __restrict__ offs,
                                                   const int* __restrict__ csr_src,
                                                   const float* __restrict__ sel,
                                                   float* __restrict__ out, int n) {
  int lane = threadIdx.x & 63;
  int g  = lane >> 4;
  int li = lane & 15;
  int c4 = li * 4;
  int wid = (blockIdx.x * blockDim.x + threadIdx.x) >> 6;
  int nw = (gridDim.x * blockDim.x) >> 6;
  float4 ak = *(const float4*)&attn[c4];
  for (int r = wid; r < n; r += nw) {
    int beg = offs[r], end = offs[r + 1];
    float4 fdv = *(const float4*)&fd[(size_t)r * 64 + c4];
    float den = 0.f;
    float4 acc; acc.x = acc.y = acc.z = acc.w = 0.f;
    int e0 = beg + g;
    int s = (e0 < end) ? csr_src[e0] : 0;
    float4 f = *(const float4*)&fs[(size_t)s * 64 + c4];
    for (int e4 = beg; e4 < end; e4 += 4) {
      bool act = (e4 + g) < end;
      int en = e4 + 4 + g;
      int sn = (en < end) ? csr_src[en] : 0;
      float4 fn = *(const float4*)&fs[(size_t)sn * 64 + c4];
      float w = ak.x * lrelu(f.x + fdv.x, 0.2f)
              + ak.y * lrelu(f.y + fdv.y, 0.2f)
              + ak.z * lrelu(f.z + fdv.z, 0.2f)
              + ak.w * lrelu(f.w + fdv.w, 0.2f);
      w += __shfl_xor(w, 1);
      w += __shfl_xor(w, 2);
      w += __shfl_xor(w, 4);
      w += __shfl_xor(w, 8);
      float p = act ? __expf(w) : 0.f;
      den += p;
      acc.x += p * f.x;
      acc.y += p * f.y;
      acc.z += p * f.z;
      acc.w += p * f.w;
      s = sn; f = fn;
    }
    #pragma unroll
    for (int o = 16; o < 64; o <<= 1) {
      den   += __shfl_xor(den, o);
      acc.x += __shfl_xor(acc.x, o);
      acc.y += __shfl_xor(acc.y, o);
      acc.z += __shfl_xor(acc.z, o);
      acc.w += __shfl_xor(acc.w, o);
    }
    if (g == 0) {
      float inv = (end > beg) ? 1.f / den : 0.f;
      float4 o4;
      o4.x = lrelu(acc.x * inv, 0.01f);
      o4.y = lrelu(acc.y * inv, 0.01f);
      o4.z = lrelu(acc.z * inv, 0.01f);
      o4.w = lrelu(acc.w * inv, 0.01f);
      if (sel) {
        float rs = o4.x + o4.y + o4.z + o4.w;
        rs += __shfl_xor(rs, 1);
        rs += __shfl_xor(rs, 2);
        rs += __shfl_xor(rs, 4);
        rs += __shfl_xor(rs, 8);
        if (rs == 0.f) o4 = *(const float4*)&sel[(size_t)r * 64 + c4];
      }
      *(float4*)&out[(size_t)r * 64 + c4] = o4;
    }
  }
}

// ---------------- fused Cheb ----------------
__global__ __launch_bounds__(256) void k_cheb_fused(const float* __restrict__ v,
                                                    const float* __restrict__ t0,
                                                    const float* __restrict__ dinv,
                                                    const int* __restrict__ offs,
                                                    const int* __restrict__ csr_src,
                                                    float* __restrict__ out,
                                                    const float* __restrict__ lamf,
                                                    int n, int mode) {
  int lane = threadIdx.x & 63;
  int g  = lane >> 4;
  int li = lane & 15;
  int c4 = li * 4;
  int wid = (blockIdx.x * blockDim.x + threadIdx.x) >> 6;
  int nw = (gridDim.x * blockDim.x) >> 6;
  float cc = 2.f / lamf[0];
  for (int r = wid; r < n; r += nw) {
    int beg = offs[r], end = offs[r + 1];
    float dr = dinv[r];
    float4 acc; acc.x = acc.y = acc.z = acc.w = 0.f;
    int e0 = beg + g;
    int s = (e0 < end) ? csr_src[e0] : 0;
    float ds = dinv[s];
    float4 f = *(const float4*)&v[(size_t)s * 64 + c4];
    for (int e4 = beg; e4 < end; e4 += 4) {
      bool act = (e4 + g) < end;
      int en = e4 + 4 + g;
      int sn = (en < end) ? csr_src[en] : 0;
      float dsn = dinv[sn];
      float4 fn = *(const float4*)&v[(size_t)sn * 64 + c4];
      float ns = act ? ds * dr : 0.f;
      acc.x += ns * f.x;
      acc.y += ns * f.y;
      acc.z += ns * f.z;
      acc.w += ns * f.w;
      s = sn; ds = dsn; f = fn;
    }
    #pragma unroll
    for (int o = 16; o < 64; o <<= 1) {
      acc.x += __shfl_xor(acc.x, o);
      acc.y += __shfl_xor(acc.y, o);
      acc.z += __shfl_xor(acc.z, o);
      acc.w += __shfl_xor(acc.w, o);
    }
    if (g == 0) {
      float4 vr = *(const float4*)&v[(size_t)r * 64 + c4];
      float4 o4;
      o4.x = cc * (vr.x - acc.x) - vr.x;
      o4.y = cc * (vr.y - acc.y) - vr.y;
      o4.z = cc * (vr.z - acc.z) - vr.z;
      o4.w = cc * (vr.w - acc.w) - vr.w;
      if (mode == 2) {
        float4 t = *(const float4*)&t0[(size_t)r * 64 + c4];
        o4.x = 2.f * o4.x - t.x;
        o4.y = 2.f * o4.y - t.y;
        o4.z = 2.f * o4.z - t.z;
        o4.w = 2.f * o4.w - t.w;
      }
      *(float4*)&out[(size_t)r * 64 + c4] = o4;
    }
  }
}

// ---------------- host ----------------
extern "C" void kernel_launch(void* const* d_in, const int* in_sizes, int n_in,
                              void* d_out, int out_size, void* d_ws, size_t ws_size,
                              hipStream_t stream) {
  const float* emb      = (const float*)d_in[0];
  const float* bn0_g    = (const float*)d_in[1];
  const float* bn0_b    = (const float*)d_in[2];
  const float* gat_Wl   = (const float*)d_in[3];
  const float* gat_bl   = (const float*)d_in[4];
  const float* gat_Wr   = (const float*)d_in[5];
  const float* gat_br   = (const float*)d_in[6];
  const float* gat_attn = (const float*)d_in[7];
  const float* cheb_W   = (const float*)d_in[8];
  const float* cheb_b   = (const float*)d_in[9];
  const float* mlp_W    = (const float*)d_in[10];
  const float* mlp_b    = (const float*)d_in[11];
  const float* mlp_g    = (const float*)d_in[12];
  const float* mlp_beta = (const float*)d_in[13];
  const float* lam      = (const float*)d_in[14];
  const int* u2i_src = (const int*)d_in[15];
  const int* u2i_dst = (const int*)d_in[16];
  const int* rc_src  = (const int*)d_in[17];
  const int* rc_dst  = (const int*)d_in[18];
  const int* i2u_src = (const int*)d_in[19];
  const int* i2u_dst = (const int*)d_in[20];
  const int* sn_src  = (const int*)d_in[22];
  const int* sn_dst  = (const int*)d_in[23];
  const int* snn_src = (const int*)d_in[24];
  const int* snn_dst = (const int*)d_in[25];
  int E_u2i = in_sizes[15], E_rc = in_sizes[17], E_i2u = in_sizes[19];
  int E_sn = in_sizes[22], E_snn = in_sizes[24];

  float* Wp = (float*)d_ws;
  size_t off = 0;
  auto alloc = [&](size_t nf) { float* p = Wp + off; off += nf; return p; };
  float* e_tot = alloc((size_t)TOTAL * 64);
  float* POOL  = alloc((size_t)600000 * 64);
  int*   csr_src = (int*)alloc(1500000);
  int*   offs    = (int*)alloc(200064);
  float* spare   = alloc(200064);
  int*   bsums   = (int*)alloc(1024);
  float* dinv  = alloc(TOTAL);
  float* sums  = alloc(896);
  auto R = [&](size_t row) { return POOL + row * 64; };
  unsigned int* tmp_e = (unsigned int*)R(520000);
  int*          Mbuf  = (int*)R(545000);
  (void)spare; (void)bsums;

  float* outP = (float*)d_out;
  float* outS = outP + (size_t)PRED * 64;
  float invP = 1.f / (float)PRED;

  auto build_csr = [&](const int* src, const int* dst, int E, int n, float* dv) {
    int nbuck = (n + 127) >> 7;
    int chunk = (E + 63) / 64;
    int L = nbuck * 64;
    k_bhist<<<64, 512, 0, stream>>>(dst, Mbuf, E, nbuck, chunk);
    k_scan_one<<<1, 1024, 0, stream>>>(Mbuf, L);
    k_bscatter<<<64, 512, 0, stream>>>(src, dst, Mbuf, tmp_e, E, nbuck, chunk);
    k_bfinal<<<nbuck, 256, 0, stream>>>(tmp_e, Mbuf, offs, csr_src, E, nbuck, n, dv);
  };
  auto gat = [&](int i, const float* fs, const float* fd, int n, const float* sel, float* out) {
    k_gat_fused<<<(n + 3) / 4, 256, 0, stream>>>(fs, fd, gat_attn + i * 64, offs, csr_src, sel, out, n);
  };
  auto gat_gemms = [&](int i, const float* A, float* fs, float* fd, int n) {
    k_gemm_dual<<<(n + 63) / 64, 256, 0, stream>>>(A, gat_Wl + i * 4096, gat_bl + i * 64,
                                                   gat_Wr + i * 4096, gat_br + i * 64, fs, fd, n);
  };
  auto cat2s = [&](const float* A1, const float* A2, const float* Wm, const float* bias,
                   float* C, int n, int slot) {
    k_gemm_cat<<<(n + 63) / 64, 256, 0, stream>>>(A1, A2, nullptr, Wm, bias, C, n, 2, 0,
                                                  sums + slot * 128);
  };

  hipMemsetAsync(sums, 0, 896 * 4, stream);

  // bn0 (slot 0): e_tot + uie=R(0)
  k_bn_stats<<<512, 256, 0, stream>>>(emb, NODES, sums);
  k_bn0_apply<<<2048, 256, 0, stream>>>(emb, e_tot, R(0), sums, bn0_g, bn0_b);

  // gat0: uie -> u2i_emb (in-place R(0))
  build_csr(u2i_src, u2i_dst, E_u2i, NUI, nullptr);
  gat_gemms(0, R(0), R(200000), R(400000), NUI);
  gat(0, R(200000), R(400000), NUI, nullptr, R(0));

  // gat1: -> iie (in-place R(0), [:PRED] used)
  build_csr(rc_src, rc_dst, E_rc, NUI, nullptr);
  gat_gemms(1, R(0), R(200000), R(400000), NUI);
  gat(1, R(200000), R(400000), NUI, nullptr, R(0));

  // gat2 + fused mask_select: soc -> R(400000)
  build_csr(i2u_src, i2u_dst, E_i2u, PRED, nullptr);
  gat_gemms(2, e_tot, R(200000), R(300000), PRED);
  gat(2, R(200000), R(300000), PRED, e_tot, R(400000));

  // gat3: sie -> R(300000)
  build_csr(sn_src, sn_dst, E_sn, PRED, nullptr);
  gat_gemms(3, R(400000), R(200000), R(500000), PRED);
  gat(3, R(200000), R(500000), PRED, nullptr, R(300000));

  // mlp0 (slot 1): raw -> R(100000); BN+lrelu -> user_item_embed at R(0)
  cat2s(R(0), R(300000), mlp_W + 0 * 8192, mlp_b + 0, R(100000), PRED, 1);
  k_bn_apply<<<2048, 256, 0, stream>>>(R(100000), R(0), sums + 128, mlp_g + 0, mlp_beta + 0, PRED, 1);
  // R(100000) now free.

  // snn CSR (+dinv fused)
  build_csr(snn_src, snn_dst, E_snn, TOTAL, dinv);

  // cheb1: e_tot -> h1 = R(340000)   (T1=R(220000), T2=R(460000))
  k_cheb_fused<<<(TOTAL + 3) / 4, 256, 0, stream>>>(e_tot, e_tot, dinv, offs, csr_src, R(220000), lam, TOTAL, 1);
  k_cheb_fused<<<(TOTAL + 3) / 4, 256, 0, stream>>>(R(220000), e_tot, dinv, offs, csr_src, R(460000), lam, TOTAL, 2);
  k_gemm_cat<<<(TOTAL + 63) / 64, 256, 0, stream>>>(e_tot, R(220000), R(460000), cheb_W, cheb_b,
                                                    R(340000), TOTAL, 3, 1, nullptr);
  // cheb2: h1 -> h2 = R(100000)  (rows 100000..219999; disjoint from R(0)[:PRED], R(220000), R(340000), R(460000))
  k_cheb_fused<<<(TOTAL + 3) / 4, 256, 0, stream>>>(R(340000), R(340000), dinv, offs, csr_src, R(220000), lam, TOTAL, 1);
  k_cheb_fused<<<(TOTAL + 3) / 4, 256, 0, stream>>>(R(220000), R(340000), dinv, offs, csr_src, R(460000), lam, TOTAL, 2);
  k_gemm_cat<<<(TOTAL + 63) / 64, 256, 0, stream>>>(R(340000), R(220000), R(460000), cheb_W, cheb_b,
                                                    R(100000), TOTAL, 3, 1, nullptr);

  // gat4: h2=R(100000) -> user_social R(460000)
  gat_gemms(4, R(100000), R(220000), R(340000), TOTAL);
  gat(4, R(220000), R(340000), TOTAL, nullptr, R(460000));

  // mlp1 (slot 2): A1 = user_item_embed R(0), A2 = e_tot -> raw h_uP R(200000)
  cat2s(R(0), e_tot, mlp_W + 1 * 8192, mlp_b + 64, R(200000), PRED, 2);

  // mlp2 (slot 3): A1 = user_social R(460000), A2 = e_tot -> raw h_uS R(300000)
  cat2s(R(460000), e_tot, mlp_W + 2 * 8192, mlp_b + 128, R(300000), PRED, 3);

  // final P (slot 4): rawA=h_uP, rawB=h_uS -> raw C R(400000); BN -> outP
  k_mlp_final<<<(PRED + 63) / 64, 256, 0, stream>>>(R(200000), R(300000),
      sums + 256, mlp_g + 64, mlp_beta + 64,
      sums + 384, mlp_g + 128, mlp_beta + 128, invP,
      mlp_W + 3 * 8192, mlp_b + 192, R(400000), PRED, sums + 512);
  k_bn_apply<<<2048, 256, 0, stream>>>(R(400000), outP, sums + 512, mlp_g + 192, mlp_beta + 192, PRED, 1);

  // final S (slot 5): rawA=h_uS, rawB=h_uP -> raw C R(100000); BN -> outS
  k_mlp_final<<<(PRED + 63) / 64, 256, 0, stream>>>(R(300000), R(200000),
      sums + 384, mlp_g + 128, mlp_beta + 128,
      sums + 256, mlp_g + 64, mlp_beta + 64, invP,
      mlp_W + 4 * 8192, mlp_b + 256, R(100000), PRED, sums + 640);
  k_bn_apply<<<2048, 256, 0, stream>>>(R(100000), outS, sums + 640, mlp_g + 256, mlp_beta + 256, PRED, 1);
}

// Round 12
// 2286.692 us; speedup vs baseline: 1.0417x; 1.0417x over previous
//
#include <hip/hip_runtime.h>
#include <math.h>

static const int PRED  = 100000;
static const int TOTAL = 120000;
static const int ITEM  = 100000;
static const int NUI   = PRED + ITEM;    // 200000
static const int NODES = TOTAL + ITEM;   // 220000
#define BN_EPS 1e-5f

__device__ inline float lrelu(float v, float s) { return fmaxf(v, s * v); }

// ---------------- batchnorm ----------------
__global__ void k_bn_stats(const float* __restrict__ x, int n, float* __restrict__ sums) {
  __shared__ float ls[256], ls2[256];
  int t = threadIdx.x;
  int col = t & 63;
  float s = 0.f, s2 = 0.f;
  for (int r = blockIdx.x * 4 + (t >> 6); r < n; r += gridDim.x * 4) {
    float v = x[(size_t)r * 64 + col];
    s += v; s2 += v * v;
  }
  ls[t] = s; ls2[t] = s2;
  __syncthreads();
  if (t < 64) {
    atomicAdd(&sums[t],      ls[t] + ls[t + 64] + ls[t + 128] + ls[t + 192]);
    atomicAdd(&sums[64 + t], ls2[t] + ls2[t + 64] + ls2[t + 128] + ls2[t + 192]);
  }
}

__global__ void k_bn_apply(const float* __restrict__ x, float* __restrict__ y,
                           const float* __restrict__ sums,
                           const float* __restrict__ g, const float* __restrict__ b,
                           int n, int relu) {
  size_t tot4 = (size_t)n * 16;
  size_t i = (size_t)blockIdx.x * blockDim.x + threadIdx.x;
  size_t st = (size_t)gridDim.x * blockDim.x;
  float inv_n = 1.f / (float)n;
  const float4* x4 = (const float4*)x;
  float4* y4 = (float4*)y;
  for (; i < tot4; i += st) {
    int c4 = (int)(i & 15) * 4;
    float4 v = x4[i];
    float4 o;
    #pragma unroll
    for (int j = 0; j < 4; ++j) {
      int c = c4 + j;
      float mean = sums[c] * inv_n;
      float var = fmaxf(sums[64 + c] * inv_n - mean * mean, 0.f);
      float vv = (j == 0) ? v.x : (j == 1) ? v.y : (j == 2) ? v.z : v.w;
      float oo = (vv - mean) * rsqrtf(var + BN_EPS) * g[c] + b[c];
      if (relu) oo = lrelu(oo, 0.01f);
      if (j == 0) o.x = oo; else if (j == 1) o.y = oo; else if (j == 2) o.z = oo; else o.w = oo;
    }
    y4[i] = o;
  }
}

__global__ void k_bn0_apply(const float* __restrict__ x, float* __restrict__ e_tot,
                            float* __restrict__ uie, const float* __restrict__ sums,
                            const float* __restrict__ g, const float* __restrict__ b) {
  size_t tot4 = (size_t)NODES * 16;
  size_t i = (size_t)blockIdx.x * blockDim.x + threadIdx.x;
  size_t st = (size_t)gridDim.x * blockDim.x;
  float inv_n = 1.f / (float)NODES;
  const float4* x4 = (const float4*)x;
  float4* e4 = (float4*)e_tot;
  float4* u4 = (float4*)uie;
  for (; i < tot4; i += st) {
    int c4 = (int)(i & 15) * 4;
    size_t row = i >> 4;
    float4 v = x4[i];
    float4 o;
    #pragma unroll
    for (int j = 0; j < 4; ++j) {
      int c = c4 + j;
      float mean = sums[c] * inv_n;
      float var = fmaxf(sums[64 + c] * inv_n - mean * mean, 0.f);
      float vv = (j == 0) ? v.x : (j == 1) ? v.y : (j == 2) ? v.z : v.w;
      float oo = (vv - mean) * rsqrtf(var + BN_EPS) * g[c] + b[c];
      if (j == 0) o.x = oo; else if (j == 1) o.y = oo; else if (j == 2) o.z = oo; else o.w = oo;
    }
    if (row < (size_t)TOTAL) e4[i] = o;
    else u4[((row - TOTAL) + PRED) * 16 + (i & 15)] = o;
    if (row < (size_t)PRED) u4[i] = o;
  }
}

// ---------------- fused GEMMs (128 rows/block, 256 threads, 4x8/thread) ----------------
__global__ __launch_bounds__(256) void k_gemm_dual(const float* __restrict__ A,
    const float* __restrict__ Wl, const float* __restrict__ bl,
    const float* __restrict__ Wr, const float* __restrict__ br,
    float* __restrict__ FS, float* __restrict__ FD, int n) {
  __shared__ float As[128][65];
  __shared__ float Ws[64][68];
  int t = threadIdx.x;
  int row0 = blockIdx.x * 128;
  for (int i = t; i < 2048; i += 256) {
    int r = i >> 4, c = (i & 15) * 4, gr = row0 + r;
    float4 a;
    if (gr < n) a = *(const float4*)&A[(size_t)gr * 64 + c];
    else { a.x = a.y = a.z = a.w = 0.f; }
    As[r][c] = a.x; As[r][c + 1] = a.y; As[r][c + 2] = a.z; As[r][c + 3] = a.w;
  }
  int cg = (t & 7) * 8;
  int rg = (t >> 3) * 4;
  for (int s = 0; s < 2; ++s) {
    const float* Wm = s ? Wr : Wl;
    const float* bias = s ? br : bl;
    __syncthreads();
    for (int i = t; i < 4096; i += 256) Ws[i >> 6][i & 63] = Wm[i];
    __syncthreads();
    float bb[8];
    *(float4*)&bb[0] = *(const float4*)&bias[cg];
    *(float4*)&bb[4] = *(const float4*)&bias[cg + 4];
    float acc[4][8];
    #pragma unroll
    for (int i = 0; i < 4; ++i)
      #pragma unroll
      for (int j = 0; j < 8; ++j) acc[i][j] = bb[j];
    for (int k = 0; k < 64; ++k) {
      float w[8], a[4];
      *(float4*)&w[0] = *(const float4*)&Ws[k][cg];
      *(float4*)&w[4] = *(const float4*)&Ws[k][cg + 4];
      #pragma unroll
      for (int i = 0; i < 4; ++i) a[i] = As[rg + i][k];
      #pragma unroll
      for (int i = 0; i < 4; ++i)
        #pragma unroll
        for (int j = 0; j < 8; ++j)
          acc[i][j] += a[i] * w[j];
    }
    float* C = s ? FD : FS;
    #pragma unroll
    for (int i = 0; i < 4; ++i) {
      int gr = row0 + rg + i;
      if (gr < n) {
        float4 o0, o1;
        o0.x = acc[i][0]; o0.y = acc[i][1]; o0.z = acc[i][2]; o0.w = acc[i][3];
        o1.x = acc[i][4]; o1.y = acc[i][5]; o1.z = acc[i][6]; o1.w = acc[i][7];
        *(float4*)&C[(size_t)gr * 64 + cg] = o0;
        *(float4*)&C[(size_t)gr * 64 + cg + 4] = o1;
      }
    }
  }
}

// concat GEMM: C = A1@W[0:64] + A2@W[64:128] (+A3@W[128:192]) + bias, optional lrelu + stats
__global__ __launch_bounds__(256) void k_gemm_cat(const float* __restrict__ A1,
    const float* __restrict__ A2, const float* __restrict__ A3,
    const float* __restrict__ Wm, const float* __restrict__ bias,
    float* __restrict__ C, int n, int nseg, int relu, float* __restrict__ stats) {
  __shared__ float As[128][65];
  __shared__ float Ws[64][68];
  __shared__ float st[128];
  int t = threadIdx.x;
  int row0 = blockIdx.x * 128;
  int cg = (t & 7) * 8;
  int rg = (t >> 3) * 4;
  float bb[8];
  *(float4*)&bb[0] = *(const float4*)&bias[cg];
  *(float4*)&bb[4] = *(const float4*)&bias[cg + 4];
  float acc[4][8];
  #pragma unroll
  for (int i = 0; i < 4; ++i)
    #pragma unroll
    for (int j = 0; j < 8; ++j) acc[i][j] = bb[j];
  for (int s = 0; s < nseg; ++s) {
    const float* A = (s == 0) ? A1 : (s == 1) ? A2 : A3;
    __syncthreads();
    for (int i = t; i < 4096; i += 256) Ws[i >> 6][i & 63] = Wm[s * 4096 + i];
    for (int i = t; i < 2048; i += 256) {
      int r = i >> 4, c = (i & 15) * 4, gr = row0 + r;
      float4 a;
      if (gr < n) a = *(const float4*)&A[(size_t)gr * 64 + c];
      else { a.x = a.y = a.z = a.w = 0.f; }
      As[r][c] = a.x; As[r][c + 1] = a.y; As[r][c + 2] = a.z; As[r][c + 3] = a.w;
    }
    __syncthreads();
    for (int k = 0; k < 64; ++k) {
      float w[8], a[4];
      *(float4*)&w[0] = *(const float4*)&Ws[k][cg];
      *(float4*)&w[4] = *(const float4*)&Ws[k][cg + 4];
      #pragma unroll
      for (int i = 0; i < 4; ++i) a[i] = As[rg + i][k];
      #pragma unroll
      for (int i = 0; i < 4; ++i)
        #pragma unroll
        for (int j = 0; j < 8; ++j)
          acc[i][j] += a[i] * w[j];
    }
  }
  float csum[8], csq[8];
  #pragma unroll
  for (int j = 0; j < 8; ++j) { csum[j] = 0.f; csq[j] = 0.f; }
  #pragma unroll
  for (int i = 0; i < 4; ++i) {
    int gr = row0 + rg + i;
    if (gr < n) {
      #pragma unroll
      for (int j = 0; j < 8; ++j) {
        float o = acc[i][j];
        if (relu) o = lrelu(o, 0.01f);
        acc[i][j] = o;
        csum[j] += o;
        csq[j] += o * o;
      }
      float4 o0, o1;
      o0.x = acc[i][0]; o0.y = acc[i][1]; o0.z = acc[i][2]; o0.w = acc[i][3];
      o1.x = acc[i][4]; o1.y = acc[i][5]; o1.z = acc[i][6]; o1.w = acc[i][7];
      *(float4*)&C[(size_t)gr * 64 + cg] = o0;
      *(float4*)&C[(size_t)gr * 64 + cg + 4] = o1;
    }
  }
  if (stats) {
    __syncthreads();
    if (t < 128) st[t] = 0.f;
    __syncthreads();
    #pragma unroll
    for (int j = 0; j < 8; ++j) {
      atomicAdd(&st[cg + j], csum[j]);
      atomicAdd(&st[64 + cg + j], csq[j]);
    }
    __syncthreads();
    if (t < 128) atomicAdd(&stats[t], st[t]);
  }
}

// out = a * b * softmax_row(a)
__global__ void k_softmax_mul(const float* __restrict__ a, const float* __restrict__ b,
                              float* __restrict__ out, int n) {
  int lane = threadIdx.x & 63;
  int wid = (blockIdx.x * blockDim.x + threadIdx.x) >> 6;
  int nw = (gridDim.x * blockDim.x) >> 6;
  for (int r = wid; r < n; r += nw) {
    size_t idx = (size_t)r * 64 + lane;
    float av = a[idx];
    float mx = av;
    for (int o = 32; o; o >>= 1) mx = fmaxf(mx, __shfl_xor(mx, o));
    float e = __expf(av - mx);
    float s = e;
    for (int o = 32; o; o >>= 1) s += __shfl_xor(s, o);
    out[idx] = av * b[idx] * (e / s);
  }
}

// ---------------- CSR build ----------------
__global__ __launch_bounds__(512) void k_bhist(const int* __restrict__ dst, int* __restrict__ M,
                                               int E, int nbuck, int chunk) {
  __shared__ int h[1600];
  int t = threadIdx.x, b = blockIdx.x;
  for (int k = t; k < nbuck; k += 512) h[k] = 0;
  __syncthreads();
  int beg = b * chunk, end = min(E, beg + chunk);
  for (int i = beg + t; i < end; i += 512) atomicAdd(&h[dst[i] >> 7], 1);
  __syncthreads();
  for (int k = t; k < nbuck; k += 512) M[k * 64 + b] = h[k];
}

__global__ __launch_bounds__(1024) void k_scan_one(int* __restrict__ cnts, int L) {
  __shared__ int wsum[16];
  __shared__ int carry_s;
  int t = threadIdx.x, lane = t & 63, w = t >> 6;
  if (t == 0) carry_s = 0;
  __syncthreads();
  for (int base = 0; base < L; base += 1024) {
    int i = base + t;
    int v = (i < L) ? cnts[i] : 0;
    int x = v;
    #pragma unroll
    for (int o = 1; o < 64; o <<= 1) {
      int y = __shfl_up(x, o);
      if (lane >= o) x += y;
    }
    if (lane == 63) wsum[w] = x;
    __syncthreads();
    int carry = carry_s;
    int wadd = 0;
    #pragma unroll
    for (int j = 0; j < 16; ++j) { int sv = wsum[j]; if (j < w) wadd += sv; }
    int incl = x + wadd + carry;
    if (i < L) cnts[i] = incl - v;
    __syncthreads();
    if (t == 1023) carry_s = incl;
    __syncthreads();
  }
}

__global__ __launch_bounds__(512) void k_bscatter(const int* __restrict__ src, const int* __restrict__ dst,
                                                  const int* __restrict__ M, unsigned int* __restrict__ tmp,
                                                  int E, int nbuck, int chunk) {
  __shared__ int cur[1600];
  int t = threadIdx.x, b = blockIdx.x;
  for (int k = t; k < nbuck; k += 512) cur[k] = M[k * 64 + b];
  __syncthreads();
  int beg = b * chunk, end = min(E, beg + chunk);
  for (int i = beg + t; i < end; i += 512) {
    int d = dst[i];
    int pos = atomicAdd(&cur[d >> 7], 1);
    tmp[pos] = ((unsigned int)(d & 127) << 25) | (unsigned int)src[i];
  }
}

__global__ __launch_bounds__(256) void k_bfinal(const unsigned int* __restrict__ tmp,
                                                const int* __restrict__ M,
                                                int* __restrict__ offs, int* __restrict__ csr,
                                                int E, int nbuck, int n,
                                                float* __restrict__ dinvOut) {
  __shared__ int h[128];
  int t = threadIdx.x, k = blockIdx.x;
  int base = M[k * 64];
  int next = (k + 1 < nbuck) ? M[(k + 1) * 64] : E;
  if (t < 128) h[t] = 0;
  __syncthreads();
  for (int i = base + t; i < next; i += 256) atomicAdd(&h[tmp[i] >> 25], 1);
  __syncthreads();
  if (t == 0) { int s = 0; for (int j = 0; j < 128; ++j) { int c = h[j]; h[j] = s; s += c; } }
  __syncthreads();
  int r0 = k << 7;
  int hstart = 0, hnext = 0;
  if (t < 128) {
    hstart = h[t];
    hnext = (t < 127) ? h[t + 1] : (next - base);
  }
  if (t < 128 && r0 + t < n) {
    offs[r0 + t] = base + hstart;
    if (dinvOut) dinvOut[r0 + t] = rsqrtf(fmaxf((float)(hnext - hstart), 1.f));
  }
  if (k == nbuck - 1 && t == 0) offs[n] = E;
  __syncthreads();
  for (int i = base + t; i < next; i += 256) {
    unsigned int v = tmp[i];
    int rl = (int)(v >> 25);
    int pos = base + atomicAdd(&h[rl], 1);
    csr[pos] = (int)(v & 0x01FFFFFFu);
  }
}

// ---------------- fused GAT v3: 8 edges/wave, 8 lanes/edge, 8 ch/lane ----------------
__global__ __launch_bounds__(256) void k_gat_fused(const float* __restrict__ fs,
                                                   const float* __restrict__ fd,
                                                   const float* __restrict__ attn,
                                                   const int* __restrict__ offs,
                                                   const int* __restrict__ csr_src,
                                                   const float* __restrict__ sel,
                                                   float* __restrict__ out, int n) {
  int lane = threadIdx.x & 63;
  int g  = lane >> 3;          // edge group 0..7
  int c8 = (lane & 7) * 8;     // channel octet
  int wid = (blockIdx.x * blockDim.x + threadIdx.x) >> 6;
  int nw = (gridDim.x * blockDim.x) >> 6;
  float4 ak0 = *(const float4*)&attn[c8];
  float4 ak1 = *(const float4*)&attn[c8 + 4];
  for (int r = wid; r < n; r += nw) {
    int beg = offs[r], end = offs[r + 1];
    float4 fd0 = *(const float4*)&fd[(size_t)r * 64 + c8];
    float4 fd1 = *(const float4*)&fd[(size_t)r * 64 + c8 + 4];
    float den = 0.f;
    float4 a0, a1;
    a0.x = a0.y = a0.z = a0.w = 0.f;
    a1.x = a1.y = a1.z = a1.w = 0.f;
    int e0 = beg + g;
    int s = (e0 < end) ? csr_src[e0] : 0;
    float4 f0 = *(const float4*)&fs[(size_t)s * 64 + c8];
    float4 f1 = *(const float4*)&fs[(size_t)s * 64 + c8 + 4];
    for (int e8 = beg; e8 < end; e8 += 8) {
      bool act = (e8 + g) < end;
      int en = e8 + 8 + g;
      int sn = (en < end) ? csr_src[en] : 0;
      float4 p0 = *(const float4*)&fs[(size_t)sn * 64 + c8];      // prefetch
      float4 p1 = *(const float4*)&fs[(size_t)sn * 64 + c8 + 4];
      float w = ak0.x * lrelu(f0.x + fd0.x, 0.2f)
              + ak0.y * lrelu(f0.y + fd0.y, 0.2f)
              + ak0.z * lrelu(f0.z + fd0.z, 0.2f)
              + ak0.w * lrelu(f0.w + fd0.w, 0.2f)
              + ak1.x * lrelu(f1.x + fd1.x, 0.2f)
              + ak1.y * lrelu(f1.y + fd1.y, 0.2f)
              + ak1.z * lrelu(f1.z + fd1.z, 0.2f)
              + ak1.w * lrelu(f1.w + fd1.w, 0.2f);
      w += __shfl_xor(w, 1);
      w += __shfl_xor(w, 2);
      w += __shfl_xor(w, 4);
      float p = act ? __expf(w) : 0.f;
      den += p;
      a0.x += p * f0.x; a0.y += p * f0.y; a0.z += p * f0.z; a0.w += p * f0.w;
      a1.x += p * f1.x; a1.y += p * f1.y; a1.z += p * f1.z; a1.w += p * f1.w;
      s = sn; f0 = p0; f1 = p1;
    }
    // merge the 8 groups (plain sums): xor 8, 16, 32
    #pragma unroll
    for (int o = 8; o < 64; o <<= 1) {
      den  += __shfl_xor(den, o);
      a0.x += __shfl_xor(a0.x, o); a0.y += __shfl_xor(a0.y, o);
      a0.z += __shfl_xor(a0.z, o); a0.w += __shfl_xor(a0.w, o);
      a1.x += __shfl_xor(a1.x, o); a1.y += __shfl_xor(a1.y, o);
      a1.z += __shfl_xor(a1.z, o); a1.w += __shfl_xor(a1.w, o);
    }
    if (g == 0) {
      float inv = (end > beg) ? 1.f / den : 0.f;
      float4 o0, o1;
      o0.x = lrelu(a0.x * inv, 0.01f); o0.y = lrelu(a0.y * inv, 0.01f);
      o0.z = lrelu(a0.z * inv, 0.01f); o0.w = lrelu(a0.w * inv, 0.01f);
      o1.x = lrelu(a1.x * inv, 0.01f); o1.y = lrelu(a1.y * inv, 0.01f);
      o1.z = lrelu(a1.z * inv, 0.01f); o1.w = lrelu(a1.w * inv, 0.01f);
      if (sel) {
        float rs = o0.x + o0.y + o0.z + o0.w + o1.x + o1.y + o1.z + o1.w;
        rs += __shfl_xor(rs, 1);
        rs += __shfl_xor(rs, 2);
        rs += __shfl_xor(rs, 4);
        if (rs == 0.f) {
          o0 = *(const float4*)&sel[(size_t)r * 64 + c8];
          o1 = *(const float4*)&sel[(size_t)r * 64 + c8 + 4];
        }
      }
      *(float4*)&out[(size_t)r * 64 + c8] = o0;
      *(float4*)&out[(size_t)r * 64 + c8 + 4] = o1;
    }
  }
}

// ---------------- fused Cheb v3: 8 edges/wave, 8 lanes/edge, 8 ch/lane ----------------
__global__ __launch_bounds__(256) void k_cheb_fused(const float* __restrict__ v,
                                                    const float* __restrict__ t0,
                                                    const float* __restrict__ dinv,
                                                    const int* __restrict__ offs,
                                                    const int* __restrict__ csr_src,
                                                    float* __restrict__ out,
                                                    const float* __restrict__ lamf,
                                                    int n, int mode) {
  int lane = threadIdx.x & 63;
  int g  = lane >> 3;
  int c8 = (lane & 7) * 8;
  int wid = (blockIdx.x * blockDim.x + threadIdx.x) >> 6;
  int nw = (gridDim.x * blockDim.x) >> 6;
  float cc = 2.f / lamf[0];
  for (int r = wid; r < n; r += nw) {
    int beg = offs[r], end = offs[r + 1];
    float dr = dinv[r];
    float4 a0, a1;
    a0.x = a0.y = a0.z = a0.w = 0.f;
    a1.x = a1.y = a1.z = a1.w = 0.f;
    int e0 = beg + g;
    int s = (e0 < end) ? csr_src[e0] : 0;
    float ds = dinv[s];
    float4 f0 = *(const float4*)&v[(size_t)s * 64 + c8];
    float4 f1 = *(const float4*)&v[(size_t)s * 64 + c8 + 4];
    for (int e8 = beg; e8 < end; e8 += 8) {
      bool act = (e8 + g) < end;
      int en = e8 + 8 + g;
      int sn = (en < end) ? csr_src[en] : 0;
      float dsn = dinv[sn];
      float4 p0 = *(const float4*)&v[(size_t)sn * 64 + c8];
      float4 p1 = *(const float4*)&v[(size_t)sn * 64 + c8 + 4];
      float ns = act ? ds * dr : 0.f;
      a0.x += ns * f0.x; a0.y += ns * f0.y; a0.z += ns * f0.z; a0.w += ns * f0.w;
      a1.x += ns * f1.x; a1.y += ns * f1.y; a1.z += ns * f1.z; a1.w += ns * f1.w;
      s = sn; ds = dsn; f0 = p0; f1 = p1;
    }
    #pragma unroll
    for (int o = 8; o < 64; o <<= 1) {
      a0.x += __shfl_xor(a0.x, o); a0.y += __shfl_xor(a0.y, o);
      a0.z += __shfl_xor(a0.z, o); a0.w += __shfl_xor(a0.w, o);
      a1.x += __shfl_xor(a1.x, o); a1.y += __shfl_xor(a1.y, o);
      a1.z += __shfl_xor(a1.z, o); a1.w += __shfl_xor(a1.w, o);
    }
    if (g == 0) {
      float4 v0 = *(const float4*)&v[(size_t)r * 64 + c8];
      float4 v1 = *(const float4*)&v[(size_t)r * 64 + c8 + 4];
      float4 o0, o1;
      o0.x = cc * (v0.x - a0.x) - v0.x; o0.y = cc * (v0.y - a0.y) - v0.y;
      o0.z = cc * (v0.z - a0.z) - v0.z; o0.w = cc * (v0.w - a0.w) - v0.w;
      o1.x = cc * (v1.x - a1.x) - v1.x; o1.y = cc * (v1.y - a1.y) - v1.y;
      o1.z = cc * (v1.z - a1.z) - v1.z; o1.w = cc * (v1.w - a1.w) - v1.w;
      if (mode == 2) {
        float4 t0a = *(const float4*)&t0[(size_t)r * 64 + c8];
        float4 t0b = *(const float4*)&t0[(size_t)r * 64 + c8 + 4];
        o0.x = 2.f * o0.x - t0a.x; o0.y = 2.f * o0.y - t0a.y;
        o0.z = 2.f * o0.z - t0a.z; o0.w = 2.f * o0.w - t0a.w;
        o1.x = 2.f * o1.x - t0b.x; o1.y = 2.f * o1.y - t0b.y;
        o1.z = 2.f * o1.z - t0b.z; o1.w = 2.f * o1.w - t0b.w;
      }
      *(float4*)&out[(size_t)r * 64 + c8] = o0;
      *(float4*)&out[(size_t)r * 64 + c8 + 4] = o1;
    }
  }
}

// ---------------- host ----------------
extern "C" void kernel_launch(void* const* d_in, const int* in_sizes, int n_in,
                              void* d_out, int out_size, void* d_ws, size_t ws_size,
                              hipStream_t stream) {
  const float* emb      = (const float*)d_in[0];
  const float* bn0_g    = (const float*)d_in[1];
  const float* bn0_b    = (const float*)d_in[2];
  const float* gat_Wl   = (const float*)d_in[3];
  const float* gat_bl   = (const float*)d_in[4];
  const float* gat_Wr   = (const float*)d_in[5];
  const float* gat_br   = (const float*)d_in[6];
  const float* gat_attn = (const float*)d_in[7];
  const float* cheb_W   = (const float*)d_in[8];
  const float* cheb_b   = (const float*)d_in[9];
  const float* mlp_W    = (const float*)d_in[10];
  const float* mlp_b    = (const float*)d_in[11];
  const float* mlp_g    = (const float*)d_in[12];
  const float* mlp_beta = (const float*)d_in[13];
  const float* lam      = (const float*)d_in[14];
  const int* u2i_src = (const int*)d_in[15];
  const int* u2i_dst = (const int*)d_in[16];
  const int* rc_src  = (const int*)d_in[17];
  const int* rc_dst  = (const int*)d_in[18];
  const int* i2u_src = (const int*)d_in[19];
  const int* i2u_dst = (const int*)d_in[20];
  const int* sn_src  = (const int*)d_in[22];
  const int* sn_dst  = (const int*)d_in[23];
  const int* snn_src = (const int*)d_in[24];
  const int* snn_dst = (const int*)d_in[25];
  int E_u2i = in_sizes[15], E_rc = in_sizes[17], E_i2u = in_sizes[19];
  int E_sn = in_sizes[22], E_snn = in_sizes[24];

  float* Wp = (float*)d_ws;
  size_t off = 0;
  auto alloc = [&](size_t nf) { float* p = Wp + off; off += nf; return p; };
  float* e_tot = alloc((size_t)TOTAL * 64);
  float* POOL  = alloc((size_t)600000 * 64);
  int*   csr_src = (int*)alloc(1500000);
  int*   offs    = (int*)alloc(200064);
  float* spare   = alloc(200064);
  int*   bsums   = (int*)alloc(1024);
  float* dinv  = alloc(TOTAL);
  float* sums  = alloc(896);                    // 7 slots x 128 floats
  auto R = [&](size_t row) { return POOL + row * 64; };
  unsigned int* tmp_e = (unsigned int*)R(520000);   // CSR scratch, dead outside builds
  int*          Mbuf  = (int*)R(545000);
  (void)spare; (void)bsums;

  float* outP = (float*)d_out;
  float* outS = outP + (size_t)PRED * 64;

  auto build_csr = [&](const int* src, const int* dst, int E, int n, float* dv) {
    int nbuck = (n + 127) >> 7;
    int chunk = (E + 63) / 64;
    int L = nbuck * 64;
    k_bhist<<<64, 512, 0, stream>>>(dst, Mbuf, E, nbuck, chunk);
    k_scan_one<<<1, 1024, 0, stream>>>(Mbuf, L);
    k_bscatter<<<64, 512, 0, stream>>>(src, dst, Mbuf, tmp_e, E, nbuck, chunk);
    k_bfinal<<<nbuck, 256, 0, stream>>>(tmp_e, Mbuf, offs, csr_src, E, nbuck, n, dv);
  };
  auto gat = [&](int i, const float* fs, const float* fd, int n, const float* sel, float* out) {
    k_gat_fused<<<(n + 3) / 4, 256, 0, stream>>>(fs, fd, gat_attn + i * 64, offs, csr_src, sel, out, n);
  };
  auto gat_gemms = [&](int i, const float* A, float* fs, float* fd, int n) {
    k_gemm_dual<<<(n + 127) / 128, 256, 0, stream>>>(A, gat_Wl + i * 4096, gat_bl + i * 64,
                                                     gat_Wr + i * 4096, gat_br + i * 64, fs, fd, n);
  };
  auto cat2s = [&](const float* A1, const float* A2, const float* Wm, const float* bias,
                   float* C, int n, int slot) {
    k_gemm_cat<<<(n + 127) / 128, 256, 0, stream>>>(A1, A2, nullptr, Wm, bias, C, n, 2, 0,
                                                    sums + slot * 128);
  };

  hipMemsetAsync(sums, 0, 896 * 4, stream);

  // bn0 (slot 0): e_tot + uie=R(0)
  k_bn_stats<<<512, 256, 0, stream>>>(emb, NODES, sums);
  k_bn0_apply<<<2048, 256, 0, stream>>>(emb, e_tot, R(0), sums, bn0_g, bn0_b);

  // gat0: uie -> u2i_emb (in-place R(0))
  build_csr(u2i_src, u2i_dst, E_u2i, NUI, nullptr);
  gat_gemms(0, R(0), R(200000), R(400000), NUI);
  gat(0, R(200000), R(400000), NUI, nullptr, R(0));

  // gat1: -> iie (in-place R(0), [:PRED] used)
  build_csr(rc_src, rc_dst, E_rc, NUI, nullptr);
  gat_gemms(1, R(0), R(200000), R(400000), NUI);
  gat(1, R(200000), R(400000), NUI, nullptr, R(0));

  // gat2 + fused mask_select: soc -> R(400000)
  build_csr(i2u_src, i2u_dst, E_i2u, PRED, nullptr);
  gat_gemms(2, e_tot, R(200000), R(300000), PRED);
  gat(2, R(200000), R(300000), PRED, e_tot, R(400000));

  // gat3: sie -> R(300000)
  build_csr(sn_src, sn_dst, E_sn, PRED, nullptr);
  gat_gemms(3, R(400000), R(200000), R(500000), PRED);
  gat(3, R(200000), R(500000), PRED, nullptr, R(300000));

  // mlp0 (slot 1): raw -> R(100000); BN+lrelu -> user_item_embed R(0)
  cat2s(R(0), R(300000), mlp_W + 0 * 8192, mlp_b + 0, R(100000), PRED, 1);
  k_bn_apply<<<2048, 256, 0, stream>>>(R(100000), R(0), sums + 128, mlp_g + 0, mlp_beta + 0, PRED, 1);

  // snn CSR (+dinv fused)
  build_csr(snn_src, snn_dst, E_snn, TOTAL, dinv);

  // cheb1: e_tot -> h1 = R(340000)  (T1=R(100000), T2=R(220000))
  k_cheb_fused<<<(TOTAL + 3) / 4, 256, 0, stream>>>(e_tot, e_tot, dinv, offs, csr_src, R(100000), lam, TOTAL, 1);
  k_cheb_fused<<<(TOTAL + 3) / 4, 256, 0, stream>>>(R(100000), e_tot, dinv, offs, csr_src, R(220000), lam, TOTAL, 2);
  k_gemm_cat<<<(TOTAL + 127) / 128, 256, 0, stream>>>(e_tot, R(100000), R(220000), cheb_W, cheb_b,
                                                      R(340000), TOTAL, 3, 1, nullptr);
  // cheb2: h1 -> h2 = R(460000)  (T1=R(100000), T2=R(220000))
  k_cheb_fused<<<(TOTAL + 3) / 4, 256, 0, stream>>>(R(340000), R(340000), dinv, offs, csr_src, R(100000), lam, TOTAL, 1);
  k_cheb_fused<<<(TOTAL + 3) / 4, 256, 0, stream>>>(R(100000), R(340000), dinv, offs, csr_src, R(220000), lam, TOTAL, 2);
  k_gemm_cat<<<(TOTAL + 127) / 128, 256, 0, stream>>>(R(340000), R(100000), R(220000), cheb_W, cheb_b,
                                                      R(460000), TOTAL, 3, 1, nullptr);

  // gat4: h2=R(460000) -> user_social R(460000) (in-place; fs/fd staged first)
  gat_gemms(4, R(460000), R(100000), R(220000), TOTAL);
  gat(4, R(100000), R(220000), TOTAL, nullptr, R(460000));

  // mlp1 (slot 2): A1 = user_item_embed R(0), A2 = e_tot -> R(100000); BN in-place
  cat2s(R(0), e_tot, mlp_W + 1 * 8192, mlp_b + 64, R(100000), PRED, 2);
  k_bn_apply<<<2048, 256, 0, stream>>>(R(100000), R(100000), sums + 256, mlp_g + 64, mlp_beta + 64, PRED, 1);

  // mlp2 (slot 3): A1 = user_social R(460000), A2 = e_tot -> R(200000); BN in-place
  cat2s(R(460000), e_tot, mlp_W + 2 * 8192, mlp_b + 128, R(200000), PRED, 3);
  k_bn_apply<<<2048, 256, 0, stream>>>(R(200000), R(200000), sums + 384, mlp_g + 128, mlp_beta + 128, PRED, 1);

  // final P (slot 4)
  k_softmax_mul<<<2048, 256, 0, stream>>>(R(100000), R(200000), R(300000), PRED);
  cat2s(R(300000), R(100000), mlp_W + 3 * 8192, mlp_b + 192, R(400000), PRED, 4);
  k_bn_apply<<<2048, 256, 0, stream>>>(R(400000), outP, sums + 512, mlp_g + 192, mlp_beta + 192, PRED, 1);

  // final S (slot 5)
  k_softmax_mul<<<2048, 256, 0, stream>>>(R(200000), R(100000), R(300000), PRED);
  cat2s(R(300000), R(200000), mlp_W + 4 * 8192, mlp_b + 256, R(400000), PRED, 5);
  k_bn_apply<<<2048, 256, 0, stream>>>(R(400000), outS, sums + 640, mlp_g + 256, mlp_beta + 256, PRED, 1);
}

// Round 13
// 2001.370 us; speedup vs baseline: 1.1902x; 1.1426x over previous
//
#include <hip/hip_runtime.h>
#include <math.h>

static const int PRED  = 100000;
static const int TOTAL = 120000;
static const int ITEM  = 100000;
static const int NUI   = PRED + ITEM;    // 200000
static const int NODES = TOTAL + ITEM;   // 220000
#define BN_EPS 1e-5f

__device__ inline float lrelu(float v, float s) { return fmaxf(v, s * v); }

// ---------------- batchnorm ----------------
__global__ void k_bn_stats(const float* __restrict__ x, int n, float* __restrict__ sums) {
  __shared__ float ls[256], ls2[256];
  int t = threadIdx.x;
  int col = t & 63;
  float s = 0.f, s2 = 0.f;
  for (int r = blockIdx.x * 4 + (t >> 6); r < n; r += gridDim.x * 4) {
    float v = x[(size_t)r * 64 + col];
    s += v; s2 += v * v;
  }
  ls[t] = s; ls2[t] = s2;
  __syncthreads();
  if (t < 64) {
    atomicAdd(&sums[t],      ls[t] + ls[t + 64] + ls[t + 128] + ls[t + 192]);
    atomicAdd(&sums[64 + t], ls2[t] + ls2[t + 64] + ls2[t + 128] + ls2[t + 192]);
  }
}

__global__ void k_bn_apply(const float* __restrict__ x, float* __restrict__ y,
                           const float* __restrict__ sums,
                           const float* __restrict__ g, const float* __restrict__ b,
                           int n, int relu) {
  size_t tot4 = (size_t)n * 16;
  size_t i = (size_t)blockIdx.x * blockDim.x + threadIdx.x;
  size_t st = (size_t)gridDim.x * blockDim.x;
  float inv_n = 1.f / (float)n;
  const float4* x4 = (const float4*)x;
  float4* y4 = (float4*)y;
  for (; i < tot4; i += st) {
    int c4 = (int)(i & 15) * 4;
    float4 v = x4[i];
    float4 o;
    #pragma unroll
    for (int j = 0; j < 4; ++j) {
      int c = c4 + j;
      float mean = sums[c] * inv_n;
      float var = fmaxf(sums[64 + c] * inv_n - mean * mean, 0.f);
      float vv = (j == 0) ? v.x : (j == 1) ? v.y : (j == 2) ? v.z : v.w;
      float oo = (vv - mean) * rsqrtf(var + BN_EPS) * g[c] + b[c];
      if (relu) oo = lrelu(oo, 0.01f);
      if (j == 0) o.x = oo; else if (j == 1) o.y = oo; else if (j == 2) o.z = oo; else o.w = oo;
    }
    y4[i] = o;
  }
}

__global__ void k_bn0_apply(const float* __restrict__ x, float* __restrict__ e_tot,
                            float* __restrict__ uie, const float* __restrict__ sums,
                            const float* __restrict__ g, const float* __restrict__ b) {
  size_t tot4 = (size_t)NODES * 16;
  size_t i = (size_t)blockIdx.x * blockDim.x + threadIdx.x;
  size_t st = (size_t)gridDim.x * blockDim.x;
  float inv_n = 1.f / (float)NODES;
  const float4* x4 = (const float4*)x;
  float4* e4 = (float4*)e_tot;
  float4* u4 = (float4*)uie;
  for (; i < tot4; i += st) {
    int c4 = (int)(i & 15) * 4;
    size_t row = i >> 4;
    float4 v = x4[i];
    float4 o;
    #pragma unroll
    for (int j = 0; j < 4; ++j) {
      int c = c4 + j;
      float mean = sums[c] * inv_n;
      float var = fmaxf(sums[64 + c] * inv_n - mean * mean, 0.f);
      float vv = (j == 0) ? v.x : (j == 1) ? v.y : (j == 2) ? v.z : v.w;
      float oo = (vv - mean) * rsqrtf(var + BN_EPS) * g[c] + b[c];
      if (j == 0) o.x = oo; else if (j == 1) o.y = oo; else if (j == 2) o.z = oo; else o.w = oo;
    }
    if (row < (size_t)TOTAL) e4[i] = o;
    else u4[((row - TOTAL) + PRED) * 16 + (i & 15)] = o;
    if (row < (size_t)PRED) u4[i] = o;
  }
}

// ---------------- fused GEMMs (128 rows/block, 256 threads, 4x8/thread) ----------------
__global__ __launch_bounds__(256) void k_gemm_dual(const float* __restrict__ A,
    const float* __restrict__ Wl, const float* __restrict__ bl,
    const float* __restrict__ Wr, const float* __restrict__ br,
    float* __restrict__ FS, float* __restrict__ FD, int n) {
  __shared__ float As[128][65];
  __shared__ float Ws[64][68];
  int t = threadIdx.x;
  int row0 = blockIdx.x * 128;
  for (int i = t; i < 2048; i += 256) {
    int r = i >> 4, c = (i & 15) * 4, gr = row0 + r;
    float4 a;
    if (gr < n) a = *(const float4*)&A[(size_t)gr * 64 + c];
    else { a.x = a.y = a.z = a.w = 0.f; }
    As[r][c] = a.x; As[r][c + 1] = a.y; As[r][c + 2] = a.z; As[r][c + 3] = a.w;
  }
  int cg = (t & 7) * 8;
  int rg = (t >> 3) * 4;
  for (int s = 0; s < 2; ++s) {
    const float* Wm = s ? Wr : Wl;
    const float* bias = s ? br : bl;
    __syncthreads();
    for (int i = t; i < 4096; i += 256) Ws[i >> 6][i & 63] = Wm[i];
    __syncthreads();
    float bb[8];
    *(float4*)&bb[0] = *(const float4*)&bias[cg];
    *(float4*)&bb[4] = *(const float4*)&bias[cg + 4];
    float acc[4][8];
    #pragma unroll
    for (int i = 0; i < 4; ++i)
      #pragma unroll
      for (int j = 0; j < 8; ++j) acc[i][j] = bb[j];
    for (int k = 0; k < 64; ++k) {
      float w[8], a[4];
      *(float4*)&w[0] = *(const float4*)&Ws[k][cg];
      *(float4*)&w[4] = *(const float4*)&Ws[k][cg + 4];
      #pragma unroll
      for (int i = 0; i < 4; ++i) a[i] = As[rg + i][k];
      #pragma unroll
      for (int i = 0; i < 4; ++i)
        #pragma unroll
        for (int j = 0; j < 8; ++j)
          acc[i][j] += a[i] * w[j];
    }
    float* C = s ? FD : FS;
    #pragma unroll
    for (int i = 0; i < 4; ++i) {
      int gr = row0 + rg + i;
      if (gr < n) {
        float4 o0, o1;
        o0.x = acc[i][0]; o0.y = acc[i][1]; o0.z = acc[i][2]; o0.w = acc[i][3];
        o1.x = acc[i][4]; o1.y = acc[i][5]; o1.z = acc[i][6]; o1.w = acc[i][7];
        *(float4*)&C[(size_t)gr * 64 + cg] = o0;
        *(float4*)&C[(size_t)gr * 64 + cg + 4] = o1;
      }
    }
  }
}

// concat GEMM: C = A1@W[0:64] + A2@W[64:128] (+A3@W[128:192]) + bias, optional lrelu + stats
__global__ __launch_bounds__(256) void k_gemm_cat(const float* __restrict__ A1,
    const float* __restrict__ A2, const float* __restrict__ A3,
    const float* __restrict__ Wm, const float* __restrict__ bias,
    float* __restrict__ C, int n, int nseg, int relu, float* __restrict__ stats) {
  __shared__ float As[128][65];
  __shared__ float Ws[64][68];
  __shared__ float st[128];
  int t = threadIdx.x;
  int row0 = blockIdx.x * 128;
  int cg = (t & 7) * 8;
  int rg = (t >> 3) * 4;
  float bb[8];
  *(float4*)&bb[0] = *(const float4*)&bias[cg];
  *(float4*)&bb[4] = *(const float4*)&bias[cg + 4];
  float acc[4][8];
  #pragma unroll
  for (int i = 0; i < 4; ++i)
    #pragma unroll
    for (int j = 0; j < 8; ++j) acc[i][j] = bb[j];
  for (int s = 0; s < nseg; ++s) {
    const float* A = (s == 0) ? A1 : (s == 1) ? A2 : A3;
    __syncthreads();
    for (int i = t; i < 4096; i += 256) Ws[i >> 6][i & 63] = Wm[s * 4096 + i];
    for (int i = t; i < 2048; i += 256) {
      int r = i >> 4, c = (i & 15) * 4, gr = row0 + r;
      float4 a;
      if (gr < n) a = *(const float4*)&A[(size_t)gr * 64 + c];
      else { a.x = a.y = a.z = a.w = 0.f; }
      As[r][c] = a.x; As[r][c + 1] = a.y; As[r][c + 2] = a.z; As[r][c + 3] = a.w;
    }
    __syncthreads();
    for (int k = 0; k < 64; ++k) {
      float w[8], a[4];
      *(float4*)&w[0] = *(const float4*)&Ws[k][cg];
      *(float4*)&w[4] = *(const float4*)&Ws[k][cg + 4];
      #pragma unroll
      for (int i = 0; i < 4; ++i) a[i] = As[rg + i][k];
      #pragma unroll
      for (int i = 0; i < 4; ++i)
        #pragma unroll
        for (int j = 0; j < 8; ++j)
          acc[i][j] += a[i] * w[j];
    }
  }
  float csum[8], csq[8];
  #pragma unroll
  for (int j = 0; j < 8; ++j) { csum[j] = 0.f; csq[j] = 0.f; }
  #pragma unroll
  for (int i = 0; i < 4; ++i) {
    int gr = row0 + rg + i;
    if (gr < n) {
      #pragma unroll
      for (int j = 0; j < 8; ++j) {
        float o = acc[i][j];
        if (relu) o = lrelu(o, 0.01f);
        acc[i][j] = o;
        csum[j] += o;
        csq[j] += o * o;
      }
      float4 o0, o1;
      o0.x = acc[i][0]; o0.y = acc[i][1]; o0.z = acc[i][2]; o0.w = acc[i][3];
      o1.x = acc[i][4]; o1.y = acc[i][5]; o1.z = acc[i][6]; o1.w = acc[i][7];
      *(float4*)&C[(size_t)gr * 64 + cg] = o0;
      *(float4*)&C[(size_t)gr * 64 + cg + 4] = o1;
    }
  }
  if (stats) {
    __syncthreads();
    if (t < 128) st[t] = 0.f;
    __syncthreads();
    #pragma unroll
    for (int j = 0; j < 8; ++j) {
      atomicAdd(&st[cg + j], csum[j]);
      atomicAdd(&st[64 + cg + j], csq[j]);
    }
    __syncthreads();
    if (t < 128) atomicAdd(&stats[t], st[t]);
  }
}

// out = a * b * softmax_row(a)
__global__ void k_softmax_mul(const float* __restrict__ a, const float* __restrict__ b,
                              float* __restrict__ out, int n) {
  int lane = threadIdx.x & 63;
  int wid = (blockIdx.x * blockDim.x + threadIdx.x) >> 6;
  int nw = (gridDim.x * blockDim.x) >> 6;
  for (int r = wid; r < n; r += nw) {
    size_t idx = (size_t)r * 64 + lane;
    float av = a[idx];
    float mx = av;
    for (int o = 32; o; o >>= 1) mx = fmaxf(mx, __shfl_xor(mx, o));
    float e = __expf(av - mx);
    float s = e;
    for (int o = 32; o; o >>= 1) s += __shfl_xor(s, o);
    out[idx] = av * b[idx] * (e / s);
  }
}

// ---------------- CSR build ----------------
__global__ __launch_bounds__(512) void k_bhist(const int* __restrict__ dst, int* __restrict__ M,
                                               int E, int nbuck, int chunk) {
  __shared__ int h[1600];
  int t = threadIdx.x, b = blockIdx.x;
  for (int k = t; k < nbuck; k += 512) h[k] = 0;
  __syncthreads();
  int beg = b * chunk, end = min(E, beg + chunk);
  for (int i = beg + t; i < end; i += 512) atomicAdd(&h[dst[i] >> 7], 1);
  __syncthreads();
  for (int k = t; k < nbuck; k += 512) M[k * 64 + b] = h[k];
}

__global__ void k_scan_part(const int* __restrict__ counts, int* __restrict__ bsums, int n) {
  __shared__ int sh[256];
  int t = threadIdx.x;
  int i = blockIdx.x * 256 + t;
  sh[t] = (i < n) ? counts[i] : 0;
  __syncthreads();
  for (int o = 128; o; o >>= 1) {
    if (t < o) sh[t] += sh[t + o];
    __syncthreads();
  }
  if (t == 0) bsums[blockIdx.x] = sh[0];
}

__global__ void k_scan_tops(int* __restrict__ bsums, int nb) {
  __shared__ int sh[256];
  int t = threadIdx.x;
  int carry = 0;
  for (int base = 0; base < nb; base += 256) {
    int i = base + t;
    int v = (i < nb) ? bsums[i] : 0;
    __syncthreads();
    sh[t] = v;
    __syncthreads();
    for (int o = 1; o < 256; o <<= 1) {
      int tv = (t >= o) ? sh[t - o] : 0;
      __syncthreads();
      sh[t] += tv;
      __syncthreads();
    }
    int incl = sh[t];
    int total = sh[255];
    if (i < nb) bsums[i] = incl - v + carry;
    carry += total;
  }
}

__global__ void k_scan_apply_ip(int* __restrict__ cnts, const int* __restrict__ bsums, int n) {
  __shared__ int sh[256];
  int t = threadIdx.x;
  int i = blockIdx.x * 256 + t;
  int v = (i < n) ? cnts[i] : 0;
  sh[t] = v;
  __syncthreads();
  for (int o = 1; o < 256; o <<= 1) {
    int tv = (t >= o) ? sh[t - o] : 0;
    __syncthreads();
    sh[t] += tv;
    __syncthreads();
  }
  if (i < n) cnts[i] = sh[t] - v + bsums[blockIdx.x];
}

__global__ __launch_bounds__(512) void k_bscatter(const int* __restrict__ src, const int* __restrict__ dst,
                                                  const int* __restrict__ M, unsigned int* __restrict__ tmp,
                                                  int E, int nbuck, int chunk) {
  __shared__ int cur[1600];
  int t = threadIdx.x, b = blockIdx.x;
  for (int k = t; k < nbuck; k += 512) cur[k] = M[k * 64 + b];
  __syncthreads();
  int beg = b * chunk, end = min(E, beg + chunk);
  for (int i = beg + t; i < end; i += 512) {
    int d = dst[i];
    int pos = atomicAdd(&cur[d >> 7], 1);
    tmp[pos] = ((unsigned int)(d & 127) << 25) | (unsigned int)src[i];
  }
}

__global__ __launch_bounds__(256) void k_bfinal(const unsigned int* __restrict__ tmp,
                                                const int* __restrict__ M,
                                                int* __restrict__ offs, int* __restrict__ csr,
                                                int E, int nbuck, int n,
                                                float* __restrict__ dinvOut) {
  __shared__ int h[128];
  int t = threadIdx.x, k = blockIdx.x;
  int base = M[k * 64];
  int next = (k + 1 < nbuck) ? M[(k + 1) * 64] : E;
  if (t < 128) h[t] = 0;
  __syncthreads();
  for (int i = base + t; i < next; i += 256) atomicAdd(&h[tmp[i] >> 25], 1);
  __syncthreads();
  if (t == 0) { int s = 0; for (int j = 0; j < 128; ++j) { int c = h[j]; h[j] = s; s += c; } }
  __syncthreads();
  int r0 = k << 7;
  int hstart = 0, hnext = 0;
  if (t < 128) {
    hstart = h[t];
    hnext = (t < 127) ? h[t + 1] : (next - base);
  }
  if (t < 128 && r0 + t < n) {
    offs[r0 + t] = base + hstart;
    if (dinvOut) dinvOut[r0 + t] = rsqrtf(fmaxf((float)(hnext - hstart), 1.f));
  }
  if (k == nbuck - 1 && t == 0) offs[n] = E;
  __syncthreads();
  for (int i = base + t; i < next; i += 256) {
    unsigned int v = tmp[i];
    int rl = (int)(v >> 25);
    int pos = base + atomicAdd(&h[rl], 1);
    csr[pos] = (int)(v & 0x01FFFFFFu);
  }
}

// ---------------- fused GAT v3: 8 edges/wave, 8 lanes/edge, 8 ch/lane ----------------
__global__ __launch_bounds__(256) void k_gat_fused(const float* __restrict__ fs,
                                                   const float* __restrict__ fd,
                                                   const float* __restrict__ attn,
                                                   const int* __restrict__ offs,
                                                   const int* __restrict__ csr_src,
                                                   const float* __restrict__ sel,
                                                   float* __restrict__ out, int n) {
  int lane = threadIdx.x & 63;
  int g  = lane >> 3;          // edge group 0..7
  int c8 = (lane & 7) * 8;     // channel octet
  int wid = (blockIdx.x * blockDim.x + threadIdx.x) >> 6;
  int nw = (gridDim.x * blockDim.x) >> 6;
  float4 ak0 = *(const float4*)&attn[c8];
  float4 ak1 = *(const float4*)&attn[c8 + 4];
  for (int r = wid; r < n; r += nw) {
    int beg = offs[r], end = offs[r + 1];
    float4 fd0 = *(const float4*)&fd[(size_t)r * 64 + c8];
    float4 fd1 = *(const float4*)&fd[(size_t)r * 64 + c8 + 4];
    float den = 0.f;
    float4 a0, a1;
    a0.x = a0.y = a0.z = a0.w = 0.f;
    a1.x = a1.y = a1.z = a1.w = 0.f;
    int e0 = beg + g;
    int s = (e0 < end) ? csr_src[e0] : 0;
    float4 f0 = *(const float4*)&fs[(size_t)s * 64 + c8];
    float4 f1 = *(const float4*)&fs[(size_t)s * 64 + c8 + 4];
    for (int e8 = beg; e8 < end; e8 += 8) {
      bool act = (e8 + g) < end;
      int en = e8 + 8 + g;
      int sn = (en < end) ? csr_src[en] : 0;
      float4 p0 = *(const float4*)&fs[(size_t)sn * 64 + c8];      // prefetch
      float4 p1 = *(const float4*)&fs[(size_t)sn * 64 + c8 + 4];
      float w = ak0.x * lrelu(f0.x + fd0.x, 0.2f)
              + ak0.y * lrelu(f0.y + fd0.y, 0.2f)
              + ak0.z * lrelu(f0.z + fd0.z, 0.2f)
              + ak0.w * lrelu(f0.w + fd0.w, 0.2f)
              + ak1.x * lrelu(f1.x + fd1.x, 0.2f)
              + ak1.y * lrelu(f1.y + fd1.y, 0.2f)
              + ak1.z * lrelu(f1.z + fd1.z, 0.2f)
              + ak1.w * lrelu(f1.w + fd1.w, 0.2f);
      w += __shfl_xor(w, 1);
      w += __shfl_xor(w, 2);
      w += __shfl_xor(w, 4);
      float p = act ? __expf(w) : 0.f;
      den += p;
      a0.x += p * f0.x; a0.y += p * f0.y; a0.z += p * f0.z; a0.w += p * f0.w;
      a1.x += p * f1.x; a1.y += p * f1.y; a1.z += p * f1.z; a1.w += p * f1.w;
      s = sn; f0 = p0; f1 = p1;
    }
    // merge the 8 groups (plain sums): xor 8, 16, 32
    #pragma unroll
    for (int o = 8; o < 64; o <<= 1) {
      den  += __shfl_xor(den, o);
      a0.x += __shfl_xor(a0.x, o); a0.y += __shfl_xor(a0.y, o);
      a0.z += __shfl_xor(a0.z, o); a0.w += __shfl_xor(a0.w, o);
      a1.x += __shfl_xor(a1.x, o); a1.y += __shfl_xor(a1.y, o);
      a1.z += __shfl_xor(a1.z, o); a1.w += __shfl_xor(a1.w, o);
    }
    if (g == 0) {
      float inv = (end > beg) ? 1.f / den : 0.f;
      float4 o0, o1;
      o0.x = lrelu(a0.x * inv, 0.01f); o0.y = lrelu(a0.y * inv, 0.01f);
      o0.z = lrelu(a0.z * inv, 0.01f); o0.w = lrelu(a0.w * inv, 0.01f);
      o1.x = lrelu(a1.x * inv, 0.01f); o1.y = lrelu(a1.y * inv, 0.01f);
      o1.z = lrelu(a1.z * inv, 0.01f); o1.w = lrelu(a1.w * inv, 0.01f);
      if (sel) {
        float rs = o0.x + o0.y + o0.z + o0.w + o1.x + o1.y + o1.z + o1.w;
        rs += __shfl_xor(rs, 1);
        rs += __shfl_xor(rs, 2);
        rs += __shfl_xor(rs, 4);
        if (rs == 0.f) {
          o0 = *(const float4*)&sel[(size_t)r * 64 + c8];
          o1 = *(const float4*)&sel[(size_t)r * 64 + c8 + 4];
        }
      }
      *(float4*)&out[(size_t)r * 64 + c8] = o0;
      *(float4*)&out[(size_t)r * 64 + c8 + 4] = o1;
    }
  }
}

// ---------------- fused Cheb v3: 8 edges/wave, 8 lanes/edge, 8 ch/lane ----------------
__global__ __launch_bounds__(256) void k_cheb_fused(const float* __restrict__ v,
                                                    const float* __restrict__ t0,
                                                    const float* __restrict__ dinv,
                                                    const int* __restrict__ offs,
                                                    const int* __restrict__ csr_src,
                                                    float* __restrict__ out,
                                                    const float* __restrict__ lamf,
                                                    int n, int mode) {
  int lane = threadIdx.x & 63;
  int g  = lane >> 3;
  int c8 = (lane & 7) * 8;
  int wid = (blockIdx.x * blockDim.x + threadIdx.x) >> 6;
  int nw = (gridDim.x * blockDim.x) >> 6;
  float cc = 2.f / lamf[0];
  for (int r = wid; r < n; r += nw) {
    int beg = offs[r], end = offs[r + 1];
    float dr = dinv[r];
    float4 a0, a1;
    a0.x = a0.y = a0.z = a0.w = 0.f;
    a1.x = a1.y = a1.z = a1.w = 0.f;
    int e0 = beg + g;
    int s = (e0 < end) ? csr_src[e0] : 0;
    float ds = dinv[s];
    float4 f0 = *(const float4*)&v[(size_t)s * 64 + c8];
    float4 f1 = *(const float4*)&v[(size_t)s * 64 + c8 + 4];
    for (int e8 = beg; e8 < end; e8 += 8) {
      bool act = (e8 + g) < end;
      int en = e8 + 8 + g;
      int sn = (en < end) ? csr_src[en] : 0;
      float dsn = dinv[sn];
      float4 p0 = *(const float4*)&v[(size_t)sn * 64 + c8];
      float4 p1 = *(const float4*)&v[(size_t)sn * 64 + c8 + 4];
      float ns = act ? ds * dr : 0.f;
      a0.x += ns * f0.x; a0.y += ns * f0.y; a0.z += ns * f0.z; a0.w += ns * f0.w;
      a1.x += ns * f1.x; a1.y += ns * f1.y; a1.z += ns * f1.z; a1.w += ns * f1.w;
      s = sn; ds = dsn; f0 = p0; f1 = p1;
    }
    #pragma unroll
    for (int o = 8; o < 64; o <<= 1) {
      a0.x += __shfl_xor(a0.x, o); a0.y += __shfl_xor(a0.y, o);
      a0.z += __shfl_xor(a0.z, o); a0.w += __shfl_xor(a0.w, o);
      a1.x += __shfl_xor(a1.x, o); a1.y += __shfl_xor(a1.y, o);
      a1.z += __shfl_xor(a1.z, o); a1.w += __shfl_xor(a1.w, o);
    }
    if (g == 0) {
      float4 v0 = *(const float4*)&v[(size_t)r * 64 + c8];
      float4 v1 = *(const float4*)&v[(size_t)r * 64 + c8 + 4];
      float4 o0, o1;
      o0.x = cc * (v0.x - a0.x) - v0.x; o0.y = cc * (v0.y - a0.y) - v0.y;
      o0.z = cc * (v0.z - a0.z) - v0.z; o0.w = cc * (v0.w - a0.w) - v0.w;
      o1.x = cc * (v1.x - a1.x) - v1.x; o1.y = cc * (v1.y - a1.y) - v1.y;
      o1.z = cc * (v1.z - a1.z) - v1.z; o1.w = cc * (v1.w - a1.w) - v1.w;
      if (mode == 2) {
        float4 t0a = *(const float4*)&t0[(size_t)r * 64 + c8];
        float4 t0b = *(const float4*)&t0[(size_t)r * 64 + c8 + 4];
        o0.x = 2.f * o0.x - t0a.x; o0.y = 2.f * o0.y - t0a.y;
        o0.z = 2.f * o0.z - t0a.z; o0.w = 2.f * o0.w - t0a.w;
        o1.x = 2.f * o1.x - t0b.x; o1.y = 2.f * o1.y - t0b.y;
        o1.z = 2.f * o1.z - t0b.z; o1.w = 2.f * o1.w - t0b.w;
      }
      *(float4*)&out[(size_t)r * 64 + c8] = o0;
      *(float4*)&out[(size_t)r * 64 + c8 + 4] = o1;
    }
  }
}

// ---------------- host ----------------
extern "C" void kernel_launch(void* const* d_in, const int* in_sizes, int n_in,
                              void* d_out, int out_size, void* d_ws, size_t ws_size,
                              hipStream_t stream) {
  const float* emb      = (const float*)d_in[0];
  const float* bn0_g    = (const float*)d_in[1];
  const float* bn0_b    = (const float*)d_in[2];
  const float* gat_Wl   = (const float*)d_in[3];
  const float* gat_bl   = (const float*)d_in[4];
  const float* gat_Wr   = (const float*)d_in[5];
  const float* gat_br   = (const float*)d_in[6];
  const float* gat_attn = (const float*)d_in[7];
  const float* cheb_W   = (const float*)d_in[8];
  const float* cheb_b   = (const float*)d_in[9];
  const float* mlp_W    = (const float*)d_in[10];
  const float* mlp_b    = (const float*)d_in[11];
  const float* mlp_g    = (const float*)d_in[12];
  const float* mlp_beta = (const float*)d_in[13];
  const float* lam      = (const float*)d_in[14];
  const int* u2i_src = (const int*)d_in[15];
  const int* u2i_dst = (const int*)d_in[16];
  const int* rc_src  = (const int*)d_in[17];
  const int* rc_dst  = (const int*)d_in[18];
  const int* i2u_src = (const int*)d_in[19];
  const int* i2u_dst = (const int*)d_in[20];
  const int* sn_src  = (const int*)d_in[22];
  const int* sn_dst  = (const int*)d_in[23];
  const int* snn_src = (const int*)d_in[24];
  const int* snn_dst = (const int*)d_in[25];
  int E_u2i = in_sizes[15], E_rc = in_sizes[17], E_i2u = in_sizes[19];
  int E_sn = in_sizes[22], E_snn = in_sizes[24];

  float* Wp = (float*)d_ws;
  size_t off = 0;
  auto alloc = [&](size_t nf) { float* p = Wp + off; off += nf; return p; };
  float* e_tot = alloc((size_t)TOTAL * 64);
  float* POOL  = alloc((size_t)600000 * 64);
  int*   csr_src = (int*)alloc(1500000);
  int*   offs    = (int*)alloc(200064);
  float* spare   = alloc(200064);
  int*   bsums   = (int*)alloc(1024);
  float* dinv  = alloc(TOTAL);
  float* sums  = alloc(896);                    // 7 slots x 128 floats
  auto R = [&](size_t row) { return POOL + row * 64; };
  unsigned int* tmp_e = (unsigned int*)R(520000);   // CSR scratch, dead outside builds
  int*          Mbuf  = (int*)R(545000);
  (void)spare;

  float* outP = (float*)d_out;
  float* outS = outP + (size_t)PRED * 64;

  auto build_csr = [&](const int* src, const int* dst, int E, int n, float* dv) {
    int nbuck = (n + 127) >> 7;
    int chunk = (E + 63) / 64;
    int L = nbuck * 64;
    int NB = (L + 255) / 256;
    k_bhist<<<64, 512, 0, stream>>>(dst, Mbuf, E, nbuck, chunk);
    k_scan_part<<<NB, 256, 0, stream>>>(Mbuf, bsums, L);
    k_scan_tops<<<1, 256, 0, stream>>>(bsums, NB);
    k_scan_apply_ip<<<NB, 256, 0, stream>>>(Mbuf, bsums, L);
    k_bscatter<<<64, 512, 0, stream>>>(src, dst, Mbuf, tmp_e, E, nbuck, chunk);
    k_bfinal<<<nbuck, 256, 0, stream>>>(tmp_e, Mbuf, offs, csr_src, E, nbuck, n, dv);
  };
  auto gat = [&](int i, const float* fs, const float* fd, int n, const float* sel, float* out) {
    k_gat_fused<<<(n + 3) / 4, 256, 0, stream>>>(fs, fd, gat_attn + i * 64, offs, csr_src, sel, out, n);
  };
  auto gat_gemms = [&](int i, const float* A, float* fs, float* fd, int n) {
    k_gemm_dual<<<(n + 127) / 128, 256, 0, stream>>>(A, gat_Wl + i * 4096, gat_bl + i * 64,
                                                     gat_Wr + i * 4096, gat_br + i * 64, fs, fd, n);
  };
  auto cat2s = [&](const float* A1, const float* A2, const float* Wm, const float* bias,
                   float* C, int n, int slot) {
    k_gemm_cat<<<(n + 127) / 128, 256, 0, stream>>>(A1, A2, nullptr, Wm, bias, C, n, 2, 0,
                                                    sums + slot * 128);
  };

  hipMemsetAsync(sums, 0, 896 * 4, stream);

  // bn0 (slot 0): e_tot + uie=R(0)
  k_bn_stats<<<512, 256, 0, stream>>>(emb, NODES, sums);
  k_bn0_apply<<<2048, 256, 0, stream>>>(emb, e_tot, R(0), sums, bn0_g, bn0_b);

  // gat0: uie -> u2i_emb (in-place R(0))
  build_csr(u2i_src, u2i_dst, E_u2i, NUI, nullptr);
  gat_gemms(0, R(0), R(200000), R(400000), NUI);
  gat(0, R(200000), R(400000), NUI, nullptr, R(0));

  // gat1: -> iie (in-place R(0), [:PRED] used)
  build_csr(rc_src, rc_dst, E_rc, NUI, nullptr);
  gat_gemms(1, R(0), R(200000), R(400000), NUI);
  gat(1, R(200000), R(400000), NUI, nullptr, R(0));

  // gat2 + fused mask_select: soc -> R(400000)
  build_csr(i2u_src, i2u_dst, E_i2u, PRED, nullptr);
  gat_gemms(2, e_tot, R(200000), R(300000), PRED);
  gat(2, R(200000), R(300000), PRED, e_tot, R(400000));

  // gat3: sie -> R(300000)
  build_csr(sn_src, sn_dst, E_sn, PRED, nullptr);
  gat_gemms(3, R(400000), R(200000), R(500000), PRED);
  gat(3, R(200000), R(500000), PRED, nullptr, R(300000));

  // mlp0 (slot 1): raw -> R(100000); BN+lrelu -> user_item_embed R(0)
  cat2s(R(0), R(300000), mlp_W + 0 * 8192, mlp_b + 0, R(100000), PRED, 1);
  k_bn_apply<<<2048, 256, 0, stream>>>(R(100000), R(0), sums + 128, mlp_g + 0, mlp_beta + 0, PRED, 1);

  // snn CSR (+dinv fused)
  build_csr(snn_src, snn_dst, E_snn, TOTAL, dinv);

  // cheb1: e_tot -> h1 = R(340000)  (T1=R(100000), T2=R(220000))
  k_cheb_fused<<<(TOTAL + 3) / 4, 256, 0, stream>>>(e_tot, e_tot, dinv, offs, csr_src, R(100000), lam, TOTAL, 1);
  k_cheb_fused<<<(TOTAL + 3) / 4, 256, 0, stream>>>(R(100000), e_tot, dinv, offs, csr_src, R(220000), lam, TOTAL, 2);
  k_gemm_cat<<<(TOTAL + 127) / 128, 256, 0, stream>>>(e_tot, R(100000), R(220000), cheb_W, cheb_b,
                                                      R(340000), TOTAL, 3, 1, nullptr);
  // cheb2: h1 -> h2 = R(460000)  (T1=R(100000), T2=R(220000))
  k_cheb_fused<<<(TOTAL + 3) / 4, 256, 0, stream>>>(R(340000), R(340000), dinv, offs, csr_src, R(100000), lam, TOTAL, 1);
  k_cheb_fused<<<(TOTAL + 3) / 4, 256, 0, stream>>>(R(100000), R(340000), dinv, offs, csr_src, R(220000), lam, TOTAL, 2);
  k_gemm_cat<<<(TOTAL + 127) / 128, 256, 0, stream>>>(R(340000), R(100000), R(220000), cheb_W, cheb_b,
                                                      R(460000), TOTAL, 3, 1, nullptr);

  // gat4: h2=R(460000) -> user_social R(460000) (in-place; fs/fd staged first)
  gat_gemms(4, R(460000), R(100000), R(220000), TOTAL);
  gat(4, R(100000), R(220000), TOTAL, nullptr, R(460000));

  // mlp1 (slot 2): A1 = user_item_embed R(0), A2 = e_tot -> R(100000); BN in-place
  cat2s(R(0), e_tot, mlp_W + 1 * 8192, mlp_b + 64, R(100000), PRED, 2);
  k_bn_apply<<<2048, 256, 0, stream>>>(R(100000), R(100000), sums + 256, mlp_g + 64, mlp_beta + 64, PRED, 1);

  // mlp2 (slot 3): A1 = user_social R(460000), A2 = e_tot -> R(200000); BN in-place
  cat2s(R(460000), e_tot, mlp_W + 2 * 8192, mlp_b + 128, R(200000), PRED, 3);
  k_bn_apply<<<2048, 256, 0, stream>>>(R(200000), R(200000), sums + 384, mlp_g + 128, mlp_beta + 128, PRED, 1);

  // final P (slot 4)
  k_softmax_mul<<<2048, 256, 0, stream>>>(R(100000), R(200000), R(300000), PRED);
  cat2s(R(300000), R(100000), mlp_W + 3 * 8192, mlp_b + 192, R(400000), PRED, 4);
  k_bn_apply<<<2048, 256, 0, stream>>>(R(400000), outP, sums + 512, mlp_g + 192, mlp_beta + 192, PRED, 1);

  // final S (slot 5)
  k_softmax_mul<<<2048, 256, 0, stream>>>(R(200000), R(100000), R(300000), PRED);
  cat2s(R(300000), R(200000), mlp_W + 4 * 8192, mlp_b + 256, R(400000), PRED, 5);
  k_bn_apply<<<2048, 256, 0, stream>>>(R(400000), outS, sums + 640, mlp_g + 256, mlp_beta + 256, PRED, 1);
}